// Round 5
// baseline (158.646 us; speedup 1.0000x reference)
//
#include <hip/hip_runtime.h>
#include <hip/hip_bf16.h>

// B=16, K=32, H=W=28, HID=OUT=64, NOPS=8
// ws layout: feat f32[512*64] | x8p f32[512*64] | W7t f32[4096] | Wtb bf16[7*4096] ([m][e][d])

typedef __attribute__((ext_vector_type(8))) short short8;
typedef __attribute__((ext_vector_type(4))) float f32x4;

__device__ __forceinline__ f32x4 mfma_bf16(short8 a, short8 b, f32x4 c) {
  return __builtin_amdgcn_mfma_f32_16x16x32_bf16(a, b, c, 0, 0, 0);
}

// float -> bf16 bits, round-to-nearest-even (finite inputs only)
__device__ __forceinline__ unsigned short f2bs(float f) {
  unsigned int u = __float_as_uint(f);
  unsigned int r = u + 0x7fffu + ((u >> 16) & 1u);
  return (unsigned short)(r >> 16);
}
// packed 2xfp32 -> 2xbf16 (v_cvt_pk_bf16_f32 on gfx950)
__device__ __forceinline__ unsigned int pk2(float x, float y) {
  union { __hip_bfloat162 h; unsigned int u; } cv;
  cv.h = __float22bfloat162_rn(make_float2(x, y));
  return cv.u;
}
// unpack 8 bf16 (16B) -> 8 f32
__device__ __forceinline__ void ub8(const short* p, float* f) {
  uint4 u = *(const uint4*)p;
  f[0] = __uint_as_float(u.x << 16); f[1] = __uint_as_float(u.x & 0xffff0000u);
  f[2] = __uint_as_float(u.y << 16); f[3] = __uint_as_float(u.y & 0xffff0000u);
  f[4] = __uint_as_float(u.z << 16); f[5] = __uint_as_float(u.z & 0xffff0000u);
  f[6] = __uint_as_float(u.w << 16); f[7] = __uint_as_float(u.w & 0xffff0000u);
}

// ---------------- kA: conv1+pool -> LDS -> conv2(MFMA)+pool -> h2f(LDS) -> fused FC -> feat ----------------
// Blocks 512-519 do eq_w prep (consumed only by k5 -> overlapped, no serialization).
__global__ __launch_bounds__(256, 2) void kA_conv(const float* __restrict__ x,
    const float* __restrict__ w1, const float* __restrict__ b1,
    const float* __restrict__ w2, const float* __restrict__ b2,
    const float* __restrict__ fcw, const float* __restrict__ fcb,
    const float* __restrict__ eqw, float* __restrict__ W7t, short* __restrict__ Wtb,
    float* __restrict__ feat) {
  const int n = blockIdx.x, t = threadIdx.x;
  if (n >= 512) {              // eq_w (d,e,m) -> W7t f32 / Wtb bf16, [e][d]
    const int m = n - 512;
    for (int idx = t; idx < 4096; idx += 256) {
      int e = idx >> 6, d = idx & 63;
      float v = eqw[d*512 + e*8 + m];
      if (m == 7) W7t[idx] = v;
      else        Wtb[m*4096 + idx] = (short)f2bs(v);
    }
    return;
  }
  __shared__ float si[30*30];
  __shared__ float sw[32*9];
  __shared__ float sb[32];
  __shared__ __align__(16) short inT[16*18*40];  // [yy][xx][cin stride 40]
  __shared__ __align__(16) float h2f[3136];      // pooled conv2 out, [c*49 + y*7 + x], f32
  __shared__ float sf4[256];                     // FC partials [w][e]
  const int wv = t >> 6, l = t & 63, quad = l >> 4, col = l & 15;

  // conv2 B fragments built in-register from w2 (no prep dependency)
  const int c_out = wv*16 + col;
  float w72[72];
  {
    const float4* src = (const float4*)(w2 + c_out*288 + quad*72);
#pragma unroll
    for (int q = 0; q < 18; ++q) {
      float4 v = src[q];
      w72[q*4+0] = v.x; w72[q*4+1] = v.y; w72[q*4+2] = v.z; w72[q*4+3] = v.w;
    }
  }
  union SU { short8 v; unsigned int u[4]; };
  short8 Bq[9];
#pragma unroll
  for (int dd = 0; dd < 9; ++dd) {
    SU b;
#pragma unroll
    for (int q = 0; q < 4; ++q)
      b.u[q] = pk2(w72[(2*q)*9 + dd], w72[(2*q+1)*9 + dd]);
    Bq[dd] = b.v;
  }
  const float bb2 = b2[c_out];

  for (int idx = t; idx < 900; idx += 256) si[idx] = 0.f;
  {
    unsigned int* zp = (unsigned int*)inT;
    for (int idx = t; idx < 5760; idx += 256) zp[idx] = 0u;
  }
  for (int idx = t; idx < 288; idx += 256) sw[idx] = w1[idx];
  if (t < 32) sb[t] = b1[t];
  __syncthreads();
  for (int idx = t; idx < 784; idx += 256) {
    int y = idx / 28, xx = idx - y*28;
    si[(y+1)*30 + xx + 1] = x[n*784 + idx];
  }
  __syncthreads();

  // conv1 + relu + maxpool, 4 channels per thread, write bf16 into inT
  {
    const int cg = t & 7;
    float wreg[4][9], breg[4];
#pragma unroll
    for (int cc = 0; cc < 4; ++cc) {
      breg[cc] = sb[cg*4 + cc];
#pragma unroll
      for (int q = 0; q < 9; ++q) wreg[cc][q] = sw[(cg*4 + cc)*9 + q];
    }
    for (int idx = t; idx < 1568; idx += 256) {
      int pos = idx >> 3;
      int py = pos / 14, px = pos - py*14;
      float pt[4][4];
#pragma unroll
      for (int r = 0; r < 4; ++r)
#pragma unroll
        for (int q = 0; q < 4; ++q)
          pt[r][q] = si[(2*py + r)*30 + 2*px + q];
      float res[4];
#pragma unroll
      for (int cc = 0; cc < 4; ++cc) {
        float best = 0.f;
#pragma unroll
        for (int a = 0; a < 2; ++a)
#pragma unroll
          for (int b3 = 0; b3 < 2; ++b3) {
            float v = breg[cc]
              + wreg[cc][0]*pt[a+0][b3+0] + wreg[cc][1]*pt[a+0][b3+1] + wreg[cc][2]*pt[a+0][b3+2]
              + wreg[cc][3]*pt[a+1][b3+0] + wreg[cc][4]*pt[a+1][b3+1] + wreg[cc][5]*pt[a+1][b3+2]
              + wreg[cc][6]*pt[a+2][b3+0] + wreg[cc][7]*pt[a+2][b3+1] + wreg[cc][8]*pt[a+2][b3+2];
            best = fmaxf(best, v);
          }
        res[cc] = best;
      }
      uint2 pkd;
      pkd.x = pk2(res[0], res[1]);
      pkd.y = pk2(res[2], res[3]);
      *(uint2*)&inT[(py+1)*720 + (px+1)*40 + cg*4] = pkd;
    }
  }
  __syncthreads();

  // conv2 via MFMA + maxpool -> h2f (LDS, f32). Wave wv produces channels [16w,16w+16).
  for (int p = 0; p < 7; ++p) {
    short8 Ar[4][3];
#pragma unroll
    for (int rr = 0; rr < 4; ++rr)
#pragma unroll
      for (int dx = 0; dx < 3; ++dx)
        Ar[rr][dx] = *(const short8*)&inT[(2*p + rr)*720 + (col + dx)*40 + quad*8];
    f32x4 a0 = {0.f,0.f,0.f,0.f}, a1 = {0.f,0.f,0.f,0.f};
#pragma unroll
    for (int dy = 0; dy < 3; ++dy)
#pragma unroll
      for (int dx = 0; dx < 3; ++dx) {
        a0 = mfma_bf16(Ar[dy][dx],     Bq[dy*3 + dx], a0);
        a1 = mfma_bf16(Ar[dy + 1][dx], Bq[dy*3 + dx], a1);
      }
#pragma unroll
    for (int a = 0; a < 2; ++a) {
      int px = quad*2 + a;
      if (px < 7) {
        float m0 = fmaxf(fmaxf(a0[2*a], a0[2*a + 1]), fmaxf(a1[2*a], a1[2*a + 1]));
        h2f[c_out*49 + p*7 + px] = fmaxf(m0 + bb2, 0.f);
      }
    }
  }
  // Fused FC 3136->64 with f32 weights read straight from fcw (L2-resident input;
  // no bf16 prepack, no unpack VALU). Wave w's k-range == channels it wrote above
  // -> wave-local, no extra barrier. h2f reads broadcast (conflict-free).
  {
    const float* Wrow = fcw + l*3136 + wv*784;   // e = l
    const float* Hrow = h2f + wv*784;
    float a0 = 0.f, a1 = 0.f, a2 = 0.f, a3 = 0.f;
#pragma unroll 7
    for (int j = 0; j < 98; ++j) {
      float4 wa = *(const float4*)&Wrow[j*8];
      float4 wb = *(const float4*)&Wrow[j*8 + 4];
      float4 hx = *(const float4*)&Hrow[j*8];
      float4 hy = *(const float4*)&Hrow[j*8 + 4];
      a0 += wa.x*hx.x + wb.x*hy.x;
      a1 += wa.y*hx.y + wb.y*hy.y;
      a2 += wa.z*hx.z + wb.z*hy.z;
      a3 += wa.w*hx.w + wb.w*hy.w;
    }
    sf4[wv*64 + l] = (a0 + a1) + (a2 + a3);
  }
  __syncthreads();
  if (t < 64) {
    float v = sf4[t] + sf4[64 + t] + sf4[128 + t] + sf4[192 + t] + fcb[t];
    feat[n*64 + t] = fmaxf(v, 0.f);
  }
}

// ---------------- k5: fused equivariant layer via bf16 MFMA -> x8p partials ----------------
// s and t7c computed in-block from the Fm tile.
// NOTE: no waves-per-EU cap — the ~180-reg live set must NOT spill (round-2: 55 MB of
// scratch traffic at the 128-VGPR cap). Grid 512 on 256 CUs is 2 blocks/CU regardless.
__global__ __launch_bounds__(256) void k5_mfma(const float* __restrict__ feat,
    const short* __restrict__ Wtb, const float* __restrict__ W7t,
    const float* __restrict__ eqb, float* __restrict__ x8p) {
  __shared__ __align__(16) float Fm[32*68];
  __shared__ __align__(16) float FI[64];
  __shared__ __align__(16) float SV[64];
  __shared__ __align__(16) float SC[64];
  __shared__ __align__(16) float TC[64];
  __shared__ __align__(16) float C0[64];
  __shared__ float C0P[128];
  __shared__ float KCf[32*68];
  __shared__ float JCf[32*68];
  __shared__ float RED[256];
  __shared__ __align__(16) short Fb[32*72];
  __shared__ __align__(16) short QPb[64*72];
  __shared__ __align__(16) short G2b[64*72];
  __shared__ __align__(16) short G3b[64*72];

  const int i = blockIdx.x, b = blockIdx.y, t = threadIdx.x;
  const int w = t >> 6, l = t & 63, quad = l >> 4, col = l & 15;

  for (int idx = t; idx < 2048; idx += 256) {
    int r = idx >> 6, d = idx & 63;
    float v = feat[b*2048 + idx];
    Fm[r*68 + d] = v;
    Fb[r*72 + d] = (short)f2bs(v);
  }
  if (t < 64) FI[t] = feat[b*2048 + i*64 + t];
  __syncthreads();

  // s = mean over set of feat
  if (t < 64) {
    float a = 0.f;
#pragma unroll
    for (int r = 0; r < 32; ++r) a += Fm[r*68 + t];
    a *= (1.f/32.f);
    SV[t] = a;
    SC[t] = a*a*a;
  }
  __syncthreads();

  // t7c[e] = sum_d s_d^3 * W7t[e][d] + eqb[e]
  if (t < 64) {
    const float* W7 = W7t + t*64;
    float acc = 0.f;
#pragma unroll
    for (int d = 0; d < 64; d += 4) {
      float4 w4 = *(const float4*)&W7[d];
      acc += SC[d]*w4.x + SC[d+1]*w4.y + SC[d+2]*w4.z + SC[d+3]*w4.w;
    }
    TC[t] = acc + eqb[t];
  }

  // P0b: QPb = fi*W0 + s*W1 ; G2b = s*(fi*W2 + s*W4) ; G3b = s*(fi*W3 + s*W5)  (bf16 weights)
  {
    const int e = t >> 2, dbase = (t & 3) * 16;
#pragma unroll
    for (int h = 0; h < 2; ++h) {
      int off = dbase + h*8;
      float w0[8], w1r[8], w2r[8], w3r[8], w4r[8], w5r[8];
      ub8(&Wtb[0*4096 + e*64 + off], w0);
      ub8(&Wtb[1*4096 + e*64 + off], w1r);
      ub8(&Wtb[2*4096 + e*64 + off], w2r);
      ub8(&Wtb[3*4096 + e*64 + off], w3r);
      ub8(&Wtb[4*4096 + e*64 + off], w4r);
      ub8(&Wtb[5*4096 + e*64 + off], w5r);
      uint4 qv, g2v, g3v;
      unsigned int* qp = &qv.x;
      unsigned int* g2p = &g2v.x;
      unsigned int* g3p = &g3v.x;
#pragma unroll
      for (int j = 0; j < 4; ++j) {
        float fi0 = FI[off + 2*j],     fi1 = FI[off + 2*j + 1];
        float s0  = SV[off + 2*j],     s1  = SV[off + 2*j + 1];
        float q0 = fi0*w0[2*j]   + s0*w1r[2*j];
        float q1 = fi1*w0[2*j+1] + s1*w1r[2*j+1];
        float a0 = s0*(fi0*w2r[2*j]   + s0*w4r[2*j]);
        float a1 = s1*(fi1*w2r[2*j+1] + s1*w4r[2*j+1]);
        float c0 = s0*(fi0*w3r[2*j]   + s0*w5r[2*j]);
        float c1 = s1*(fi1*w3r[2*j+1] + s1*w5r[2*j+1]);
        qp[j]  = pk2(q0, q1);
        g2p[j] = pk2(a0, a1);
        g3p[j] = pk2(c0, c1);
      }
      *(uint4*)&QPb[e*72 + off] = qv;
      *(uint4*)&G2b[e*72 + off] = g2v;
      *(uint4*)&G3b[e*72 + off] = g3v;
    }
  }
  if (t < 128) {
    int e = t & 63, dh = t >> 6;
    const short* W6 = Wtb + 6*4096 + e*64 + dh*32;
    float a = 0.f;
#pragma unroll
    for (int g = 0; g < 4; ++g) {
      float wf[8];
      ub8(&W6[g*8], wf);
#pragma unroll
      for (int dd = 0; dd < 8; ++dd) {
        int d = dh*32 + g*8 + dd;
        float sd = SV[d];
        a += sd*sd*FI[d]*wf[dd];
      }
    }
    C0P[dh*64 + e] = a;
  }
  __syncthreads();

  if (w < 2) {
    const short* G = w ? G3b : G2b;
    float* DST = w ? JCf : KCf;
    short8 Bf[4][2];
#pragma unroll
    for (int n = 0; n < 4; ++n)
#pragma unroll
      for (int s2 = 0; s2 < 2; ++s2)
        Bf[n][s2] = *(const short8*)&G[(n*16 + col)*72 + s2*32 + quad*8];
#pragma unroll
    for (int m = 0; m < 2; ++m) {
      short8 A0 = *(const short8*)&Fb[(m*16 + col)*72 + quad*8];
      short8 A1 = *(const short8*)&Fb[(m*16 + col)*72 + 32 + quad*8];
#pragma unroll
      for (int n = 0; n < 4; ++n) {
        f32x4 z = {0.f, 0.f, 0.f, 0.f};
        f32x4 ac = mfma_bf16(A1, Bf[n][1], mfma_bf16(A0, Bf[n][0], z));
#pragma unroll
        for (int r = 0; r < 4; ++r)
          DST[(m*16 + quad*4 + r)*68 + n*16 + col] = ac[r];
      }
    }
  } else if (w == 2) {
    C0[l] = C0P[l] + C0P[64 + l] + TC[l];
  }
  __syncthreads();

  float kcv[2][4][4];
#pragma unroll
  for (int kb2 = 0; kb2 < 2; ++kb2)
#pragma unroll
    for (int r = 0; r < 4; ++r)
#pragma unroll
      for (int n = 0; n < 4; ++n)
        kcv[kb2][r][n] = KCf[(kb2*16 + quad*4 + r)*68 + n*16 + col];
  short8 Bq[4][2];
#pragma unroll
  for (int n = 0; n < 4; ++n)
#pragma unroll
    for (int s2 = 0; s2 < 2; ++s2)
      Bq[n][s2] = *(const short8*)&QPb[(n*16 + col)*72 + s2*32 + quad*8];

  float4 fkv[2][4];
#pragma unroll
  for (int kb2 = 0; kb2 < 2; ++kb2) {
    const float* fk = &Fm[(kb2*16 + col)*68 + quad*8];
    fkv[kb2][0] = *(const float4*)(fk);
    fkv[kb2][1] = *(const float4*)(fk + 4);
    fkv[kb2][2] = *(const float4*)(fk + 32);
    fkv[kb2][3] = *(const float4*)(fk + 36);
  }

  float sum[4] = {0.f, 0.f, 0.f, 0.f};
  union SU { short8 v; unsigned int u[4]; };

#pragma unroll
  for (int jj = 0; jj < 8; ++jj) {
    // jcq re-read per-jj from LDS (keeps peak VGPR pressure under the no-spill line)
    float jcq[4];
#pragma unroll
    for (int n = 0; n < 4; ++n)
      jcq[n] = JCf[(w*8 + jj)*68 + n*16 + col] + C0[n*16 + col];
    const float* fj = &Fm[(w*8 + jj)*68 + quad*8];
    float4 j0 = *(const float4*)(fj);
    float4 j1 = *(const float4*)(fj + 4);
    float4 j2 = *(const float4*)(fj + 32);
    float4 j3 = *(const float4*)(fj + 36);
#pragma unroll
    for (int kb2 = 0; kb2 < 2; ++kb2) {
      float4 k0 = fkv[kb2][0], k1 = fkv[kb2][1];
      float4 k2v = fkv[kb2][2], k3v = fkv[kb2][3];
      SU A0, A1;
      A0.u[0] = pk2(j0.x*k0.x, j0.y*k0.y);
      A0.u[1] = pk2(j0.z*k0.z, j0.w*k0.w);
      A0.u[2] = pk2(j1.x*k1.x, j1.y*k1.y);
      A0.u[3] = pk2(j1.z*k1.z, j1.w*k1.w);
      A1.u[0] = pk2(j2.x*k2v.x, j2.y*k2v.y);
      A1.u[1] = pk2(j2.z*k2v.z, j2.w*k2v.w);
      A1.u[2] = pk2(j3.x*k3v.x, j3.y*k3v.y);
      A1.u[3] = pk2(j3.z*k3v.z, j3.w*k3v.w);
      f32x4 ac[4];
#pragma unroll
      for (int n = 0; n < 4; ++n) {
        f32x4 z = {0.f, 0.f, 0.f, 0.f};
        ac[n] = mfma_bf16(A1.v, Bq[n][1], mfma_bf16(A0.v, Bq[n][0], z));
      }
#pragma unroll
      for (int n = 0; n < 4; ++n)
#pragma unroll
        for (int r = 0; r < 4; ++r) {
          float v = ac[n][r] + kcv[kb2][r][n] + jcq[n];
          sum[n] += fmaxf(v, 0.f);
        }
    }
  }

#pragma unroll
  for (int n = 0; n < 4; ++n) {
    float v = sum[n];
    v += __shfl_xor(v, 16, 64);
    v += __shfl_xor(v, 32, 64);
    if (l < 16) RED[w*64 + n*16 + l] = v;
  }
  __syncthreads();
  if (t < 64) {
    float tot = RED[t] + RED[64 + t] + RED[128 + t] + RED[192 + t];
    x8p[(b*32 + i)*64 + t] = tot;            // non-atomic partial
  }
}

// ---------------- k6: reduce x8p over i; x9 = relu(x8/K^3); out = x9 @ out_w.T + out_b ----------------
__global__ __launch_bounds__(64) void k6_out(const float* __restrict__ x8p,
    const float* __restrict__ ow, const float* __restrict__ ob,
    float* __restrict__ out) {
  const int bb = blockIdx.x, t = threadIdx.x;
  float a = 0.f;
#pragma unroll
  for (int i = 0; i < 32; ++i) a += x8p[(bb*32 + i)*64 + t];
  float v = fmaxf(a * (1.f/32768.f), 0.f) * ow[t];
#pragma unroll
  for (int off = 32; off > 0; off >>= 1) v += __shfl_down(v, off, 64);
  if (t == 0) out[bb] = v + ob[0];
}

extern "C" void kernel_launch(void* const* d_in, const int* in_sizes, int n_in,
                              void* d_out, int out_size, void* d_ws, size_t ws_size,
                              hipStream_t stream) {
  const float* x   = (const float*)d_in[0];
  const float* c1w = (const float*)d_in[1];
  const float* c1b = (const float*)d_in[2];
  const float* c2w = (const float*)d_in[3];
  const float* c2b = (const float*)d_in[4];
  const float* fcw = (const float*)d_in[5];
  const float* fcb = (const float*)d_in[6];
  const float* eqw = (const float*)d_in[7];
  const float* eqb = (const float*)d_in[8];
  const float* ow  = (const float*)d_in[9];
  const float* ob  = (const float*)d_in[10];
  float* out = (float*)d_out;

  float* feat = (float*)d_ws;             // 512*64 f32
  float* x8p  = feat + 32768;             // 512*64 f32
  float* W7t  = x8p + 32768;              // 4096 f32
  short* Wtb  = (short*)(W7t + 4096);     // 7*4096 bf16
  (void)in_sizes; (void)n_in; (void)out_size; (void)ws_size;

  hipLaunchKernelGGL(kA_conv, dim3(520), dim3(256), 0, stream,
                     x, c1w, c1b, c2w, c2b, fcw, fcb, eqw, W7t, Wtb, feat);
  hipLaunchKernelGGL(k5_mfma, dim3(32, 16), dim3(256), 0, stream,
                     feat, Wtb, W7t, eqb, x8p);
  hipLaunchKernelGGL(k6_out,  dim3(16),  dim3(64),  0, stream, x8p, ow, ob, out);
}

// Round 6
// 128.504 us; speedup vs baseline: 1.2346x; 1.2346x over previous
//
#include <hip/hip_runtime.h>
#include <hip/hip_bf16.h>

// B=16, K=32, H=W=28, HID=OUT=64, NOPS=8
// ws: feat f32[512*64] | x8p f32[512*64] | W7t f32[4096] | Wtb bf16[7*4096] ([m][e][d])
//     | w2p bf16[18432] | fcwt bf16[3136*64] ([k][e]) | s f32[1024] | t7c f32[1024]

typedef __attribute__((ext_vector_type(8))) short short8;
typedef __attribute__((ext_vector_type(4))) float f32x4;

__device__ __forceinline__ f32x4 mfma_bf16(short8 a, short8 b, f32x4 c) {
  return __builtin_amdgcn_mfma_f32_16x16x32_bf16(a, b, c, 0, 0, 0);
}

// float -> bf16 bits, round-to-nearest-even (finite inputs only)
__device__ __forceinline__ unsigned short f2bs(float f) {
  unsigned int u = __float_as_uint(f);
  unsigned int r = u + 0x7fffu + ((u >> 16) & 1u);
  return (unsigned short)(r >> 16);
}
// packed 2xfp32 -> 2xbf16 (v_cvt_pk_bf16_f32 on gfx950)
__device__ __forceinline__ unsigned int pk2(float x, float y) {
  union { __hip_bfloat162 h; unsigned int u; } cv;
  cv.h = __float22bfloat162_rn(make_float2(x, y));
  return cv.u;
}
// unpack 8 bf16 (16B) -> 8 f32
__device__ __forceinline__ void ub8(const short* p, float* f) {
  uint4 u = *(const uint4*)p;
  f[0] = __uint_as_float(u.x << 16); f[1] = __uint_as_float(u.x & 0xffff0000u);
  f[2] = __uint_as_float(u.y << 16); f[3] = __uint_as_float(u.y & 0xffff0000u);
  f[4] = __uint_as_float(u.z << 16); f[5] = __uint_as_float(u.z & 0xffff0000u);
  f[6] = __uint_as_float(u.w << 16); f[7] = __uint_as_float(u.w & 0xffff0000u);
}

// ---------------- k0: weight prep (eq_w, conv2 pack, FC transpose to [k][e] bf16) ----------------
__global__ __launch_bounds__(256) void k0_prep(const float* __restrict__ eqw,
    const float* __restrict__ w2, const float* __restrict__ fcw,
    float* __restrict__ W7t, short* __restrict__ Wtb,
    short* __restrict__ w2p, short* __restrict__ fcwt) {
  const int b = blockIdx.x, t = threadIdx.x;
  if (b < 8) {                 // eq_w (d,e,m) -> W7t f32 / Wtb bf16, [e][d]
    const int m = b;
    for (int idx = t; idx < 4096; idx += 256) {
      int e = idx >> 6, d = idx & 63;
      float v = eqw[d*512 + e*8 + m];
      if (m == 7) W7t[idx] = v;
      else        Wtb[m*4096 + idx] = (short)f2bs(v);
    }
  } else if (b == 8) {
    // conv2 weights -> B-fragment layout: w2p[((dd*4+quad)*64 + cout)*8 + s]
    for (int idx = t; idx < 18432; idx += 256) {
      int s2 = idx & 7, c = (idx >> 3) & 63, quad = (idx >> 9) & 3, dd = idx >> 11;
      w2p[idx] = (short)f2bs(w2[c*288 + (quad*8 + s2)*9 + dd]);
    }
  } else {                     // fc_w [e][k] f32 -> fcwt [k][e] bf16 (coalesced writes)
    int base = (b - 9)*12544 + t;
    for (int q = 0; q < 49; ++q) {
      int idx = base + q*256;          // idx = k*64 + e
      int k = idx >> 6, e = idx & 63;
      fcwt[idx] = (short)f2bs(fcw[e*3136 + k]);
    }
  }
}

// ---------------- kA: conv1+pool -> LDS -> conv2(MFMA)+pool -> h2f(LDS) -> coalesced FC -> feat ----------------
__global__ __launch_bounds__(256, 2) void kA_conv(const float* __restrict__ x,
    const float* __restrict__ w1, const float* __restrict__ b1,
    const short* __restrict__ w2p, const float* __restrict__ b2,
    const short* __restrict__ fcwt, const float* __restrict__ fcb,
    float* __restrict__ feat) {
  const int n = blockIdx.x, t = threadIdx.x;
  __shared__ float si[30*30];
  __shared__ float sw[32*9];
  __shared__ float sb[32];
  __shared__ __align__(16) short inT[16*18*40];  // [yy][xx][cin stride 40]
  __shared__ __align__(16) float h2f[3136];      // pooled conv2 out, [c*49 + y*7 + x], f32
  __shared__ float sf4[256];                     // FC partials [w][e]
  const int wv = t >> 6, l = t & 63, quad = l >> 4, col = l & 15;

  // conv2 B fragments: pre-packed by k0, 9 coalesced 16B loads (R2-proven, VGPR-light)
  const int c_out = wv*16 + col;
  short8 Bq[9];
  {
    const short8* wp = (const short8*)w2p + quad*64 + c_out;
#pragma unroll
    for (int dd = 0; dd < 9; ++dd) Bq[dd] = wp[dd*256];
  }
  const float bb2 = b2[c_out];

  for (int idx = t; idx < 900; idx += 256) si[idx] = 0.f;
  {
    unsigned int* zp = (unsigned int*)inT;
    for (int idx = t; idx < 5760; idx += 256) zp[idx] = 0u;
  }
  for (int idx = t; idx < 288; idx += 256) sw[idx] = w1[idx];
  if (t < 32) sb[t] = b1[t];
  __syncthreads();
  for (int idx = t; idx < 784; idx += 256) {
    int y = idx / 28, xx = idx - y*28;
    si[(y+1)*30 + xx + 1] = x[n*784 + idx];
  }
  __syncthreads();

  // conv1 + relu + maxpool, 4 channels per thread, write bf16 into inT
  {
    const int cg = t & 7;
    float wreg[4][9], breg[4];
#pragma unroll
    for (int cc = 0; cc < 4; ++cc) {
      breg[cc] = sb[cg*4 + cc];
#pragma unroll
      for (int q = 0; q < 9; ++q) wreg[cc][q] = sw[(cg*4 + cc)*9 + q];
    }
    for (int idx = t; idx < 1568; idx += 256) {
      int pos = idx >> 3;
      int py = pos / 14, px = pos - py*14;
      float pt[4][4];
#pragma unroll
      for (int r = 0; r < 4; ++r)
#pragma unroll
        for (int q = 0; q < 4; ++q)
          pt[r][q] = si[(2*py + r)*30 + 2*px + q];
      float res[4];
#pragma unroll
      for (int cc = 0; cc < 4; ++cc) {
        float best = 0.f;
#pragma unroll
        for (int a = 0; a < 2; ++a)
#pragma unroll
          for (int b3 = 0; b3 < 2; ++b3) {
            float v = breg[cc]
              + wreg[cc][0]*pt[a+0][b3+0] + wreg[cc][1]*pt[a+0][b3+1] + wreg[cc][2]*pt[a+0][b3+2]
              + wreg[cc][3]*pt[a+1][b3+0] + wreg[cc][4]*pt[a+1][b3+1] + wreg[cc][5]*pt[a+1][b3+2]
              + wreg[cc][6]*pt[a+2][b3+0] + wreg[cc][7]*pt[a+2][b3+1] + wreg[cc][8]*pt[a+2][b3+2];
            best = fmaxf(best, v);
          }
        res[cc] = best;
      }
      uint2 pkd;
      pkd.x = pk2(res[0], res[1]);
      pkd.y = pk2(res[2], res[3]);
      *(uint2*)&inT[(py+1)*720 + (px+1)*40 + cg*4] = pkd;
    }
  }
  __syncthreads();

  // conv2 via MFMA + maxpool -> h2f (LDS, f32). Wave wv produces channels [16w,16w+16).
  for (int p = 0; p < 7; ++p) {
    short8 Ar[4][3];
#pragma unroll
    for (int rr = 0; rr < 4; ++rr)
#pragma unroll
      for (int dx = 0; dx < 3; ++dx)
        Ar[rr][dx] = *(const short8*)&inT[(2*p + rr)*720 + (col + dx)*40 + quad*8];
    f32x4 a0 = {0.f,0.f,0.f,0.f}, a1 = {0.f,0.f,0.f,0.f};
#pragma unroll
    for (int dy = 0; dy < 3; ++dy)
#pragma unroll
      for (int dx = 0; dx < 3; ++dx) {
        a0 = mfma_bf16(Ar[dy][dx],     Bq[dy*3 + dx], a0);
        a1 = mfma_bf16(Ar[dy + 1][dx], Bq[dy*3 + dx], a1);
      }
#pragma unroll
    for (int a = 0; a < 2; ++a) {
      int px = quad*2 + a;
      if (px < 7) {
        float m0 = fmaxf(fmaxf(a0[2*a], a0[2*a + 1]), fmaxf(a1[2*a], a1[2*a + 1]));
        h2f[c_out*49 + p*7 + px] = fmaxf(m0 + bb2, 0.f);
      }
    }
  }
  // Coalesced fused FC 3136->64 with fcwt [k][e] bf16.
  // Lane l: g = l>>3 (k-offset within octet), s = l&7 (e-octet). Wave wv covers
  // k in [784wv, 784wv+784) == exactly the h2f channels it wrote (wave-local, no barrier).
  // Each wave-load = 1KB contiguous (16B/lane) -> fully coalesced L2 reads.
  {
    const int g = l >> 3, s = l & 7;
    const short* Wp = fcwt + (wv*784 + g)*64 + s*8;
    const float* Hp = h2f + wv*784 + g;
    float acc[8] = {0.f,0.f,0.f,0.f,0.f,0.f,0.f,0.f};
#pragma unroll 7
    for (int j = 0; j < 98; ++j) {
      float wf[8]; ub8(Wp + j*512, wf);
      float hk = Hp[j*8];
#pragma unroll
      for (int q = 0; q < 8; ++q) acc[q] += wf[q] * hk;
    }
#pragma unroll
    for (int q = 0; q < 8; ++q) {
      acc[q] += __shfl_xor(acc[q], 8, 64);
      acc[q] += __shfl_xor(acc[q], 16, 64);
      acc[q] += __shfl_xor(acc[q], 32, 64);
    }
    if (g == 0) {
#pragma unroll
      for (int q = 0; q < 8; ++q) sf4[wv*64 + s*8 + q] = acc[q];
    }
  }
  __syncthreads();
  if (t < 64) {
    float v = sf4[t] + sf4[64 + t] + sf4[128 + t] + sf4[192 + t] + fcb[t];
    feat[n*64 + t] = fmaxf(v, 0.f);
  }
}

// ---------------- k4b: s = mean_K(feat), t7c = (s^3)@W7 + eqb ----------------
__global__ __launch_bounds__(256) void k4b(const float* __restrict__ feat,
    const float* __restrict__ W7t, const float* __restrict__ eqb,
    float* __restrict__ s, float* __restrict__ t7c) {
  __shared__ __align__(16) float sf[2048];
  __shared__ float ss[64];
  const int b = blockIdx.x, t = threadIdx.x;
  for (int v4 = t; v4 < 512; v4 += 256)
    *(float4*)&sf[v4*4] = *(const float4*)&feat[b*2048 + v4*4];
  __syncthreads();
  if (t < 64) {
    float a = 0.f;
#pragma unroll
    for (int r = 0; r < 32; ++r) a += sf[r*64 + t];
    a *= (1.f/32.f);
    s[b*64 + t] = a;
    ss[t] = a;
  }
  __syncthreads();
  if (t < 64) {
    const float* W7 = W7t + t*64;   // [e=t][d]
    float t7 = 0.f;
    for (int d = 0; d < 64; ++d) {
      float sv = ss[d];
      t7 += sv*sv*sv * W7[d];
    }
    t7c[b*64 + t] = t7 + eqb[t];
  }
}

// ---------------- k5: fused equivariant layer via bf16 MFMA -> x8p partials (R0-verbatim) ----------------
__global__ __launch_bounds__(256, 2) void k5_mfma(const float* __restrict__ feat,
    const float* __restrict__ s_, const short* __restrict__ Wtb,
    const float* __restrict__ t7c, float* __restrict__ x8p) {
  __shared__ __align__(16) float Fm[32*68];
  __shared__ __align__(16) float FI[64];
  __shared__ __align__(16) float SV[64];
  __shared__ __align__(16) float C0[64];
  __shared__ float C0P[128];
  __shared__ float KCf[32*68];
  __shared__ float JCf[32*68];
  __shared__ float RED[256];
  __shared__ __align__(16) short Fb[32*72];
  __shared__ __align__(16) short QPb[64*72];
  __shared__ __align__(16) short G2b[64*72];
  __shared__ __align__(16) short G3b[64*72];

  const int i = blockIdx.x, b = blockIdx.y, t = threadIdx.x;
  const int w = t >> 6, l = t & 63, quad = l >> 4, col = l & 15;

  for (int idx = t; idx < 2048; idx += 256) {
    int r = idx >> 6, d = idx & 63;
    float v = feat[b*2048 + idx];
    Fm[r*68 + d] = v;
    Fb[r*72 + d] = (short)f2bs(v);
  }
  if (t < 64) { FI[t] = feat[b*2048 + i*64 + t]; SV[t] = s_[b*64 + t]; }
  __syncthreads();

  // P0b: QPb = fi*W0 + s*W1 ; G2b = s*(fi*W2 + s*W4) ; G3b = s*(fi*W3 + s*W5)  (bf16 weights)
  {
    const int e = t >> 2, dbase = (t & 3) * 16;
#pragma unroll
    for (int h = 0; h < 2; ++h) {
      int off = dbase + h*8;
      float w0[8], w1[8], w2[8], w3[8], w4[8], w5[8];
      ub8(&Wtb[0*4096 + e*64 + off], w0);
      ub8(&Wtb[1*4096 + e*64 + off], w1);
      ub8(&Wtb[2*4096 + e*64 + off], w2);
      ub8(&Wtb[3*4096 + e*64 + off], w3);
      ub8(&Wtb[4*4096 + e*64 + off], w4);
      ub8(&Wtb[5*4096 + e*64 + off], w5);
      uint4 qv, g2v, g3v;
      unsigned int* qp = &qv.x;
      unsigned int* g2p = &g2v.x;
      unsigned int* g3p = &g3v.x;
#pragma unroll
      for (int j = 0; j < 4; ++j) {
        float fi0 = FI[off + 2*j],     fi1 = FI[off + 2*j + 1];
        float s0  = SV[off + 2*j],     s1  = SV[off + 2*j + 1];
        float q0 = fi0*w0[2*j]   + s0*w1[2*j];
        float q1 = fi1*w0[2*j+1] + s1*w1[2*j+1];
        float a0 = s0*(fi0*w2[2*j]   + s0*w4[2*j]);
        float a1 = s1*(fi1*w2[2*j+1] + s1*w4[2*j+1]);
        float c0 = s0*(fi0*w3[2*j]   + s0*w5[2*j]);
        float c1 = s1*(fi1*w3[2*j+1] + s1*w5[2*j+1]);
        qp[j]  = pk2(q0, q1);
        g2p[j] = pk2(a0, a1);
        g3p[j] = pk2(c0, c1);
      }
      *(uint4*)&QPb[e*72 + off] = qv;
      *(uint4*)&G2b[e*72 + off] = g2v;
      *(uint4*)&G3b[e*72 + off] = g3v;
    }
  }
  if (t < 128) {
    int e = t & 63, dh = t >> 6;
    const short* W6 = Wtb + 6*4096 + e*64 + dh*32;
    float a = 0.f;
#pragma unroll
    for (int g = 0; g < 4; ++g) {
      float wf[8];
      ub8(&W6[g*8], wf);
#pragma unroll
      for (int dd = 0; dd < 8; ++dd) {
        int d = dh*32 + g*8 + dd;
        float sd = SV[d];
        a += sd*sd*FI[d]*wf[dd];
      }
    }
    C0P[dh*64 + e] = a;
  }
  __syncthreads();

  if (w < 2) {
    const short* G = w ? G3b : G2b;
    float* DST = w ? JCf : KCf;
    short8 Bf[4][2];
#pragma unroll
    for (int n = 0; n < 4; ++n)
#pragma unroll
      for (int s2 = 0; s2 < 2; ++s2)
        Bf[n][s2] = *(const short8*)&G[(n*16 + col)*72 + s2*32 + quad*8];
#pragma unroll
    for (int m = 0; m < 2; ++m) {
      short8 A0 = *(const short8*)&Fb[(m*16 + col)*72 + quad*8];
      short8 A1 = *(const short8*)&Fb[(m*16 + col)*72 + 32 + quad*8];
#pragma unroll
      for (int n = 0; n < 4; ++n) {
        f32x4 z = {0.f, 0.f, 0.f, 0.f};
        f32x4 ac = mfma_bf16(A1, Bf[n][1], mfma_bf16(A0, Bf[n][0], z));
#pragma unroll
        for (int r = 0; r < 4; ++r)
          DST[(m*16 + quad*4 + r)*68 + n*16 + col] = ac[r];
      }
    }
  } else if (w == 2) {
    C0[l] = C0P[l] + C0P[64 + l] + t7c[b*64 + l];
  }
  __syncthreads();

  float c0v[4];
#pragma unroll
  for (int n = 0; n < 4; ++n) c0v[n] = C0[n*16 + col];
  float jcq[8][4];
#pragma unroll
  for (int jj = 0; jj < 8; ++jj)
#pragma unroll
    for (int n = 0; n < 4; ++n)
      jcq[jj][n] = JCf[(w*8 + jj)*68 + n*16 + col] + c0v[n];
  float kcv[2][4][4];
#pragma unroll
  for (int kb2 = 0; kb2 < 2; ++kb2)
#pragma unroll
    for (int r = 0; r < 4; ++r)
#pragma unroll
      for (int n = 0; n < 4; ++n)
        kcv[kb2][r][n] = KCf[(kb2*16 + quad*4 + r)*68 + n*16 + col];
  short8 Bq[4][2];
#pragma unroll
  for (int n = 0; n < 4; ++n)
#pragma unroll
    for (int s2 = 0; s2 < 2; ++s2)
      Bq[n][s2] = *(const short8*)&QPb[(n*16 + col)*72 + s2*32 + quad*8];

  float4 fkv[2][4];
#pragma unroll
  for (int kb2 = 0; kb2 < 2; ++kb2) {
    const float* fk = &Fm[(kb2*16 + col)*68 + quad*8];
    fkv[kb2][0] = *(const float4*)(fk);
    fkv[kb2][1] = *(const float4*)(fk + 4);
    fkv[kb2][2] = *(const float4*)(fk + 32);
    fkv[kb2][3] = *(const float4*)(fk + 36);
  }

  float sum[4] = {0.f, 0.f, 0.f, 0.f};
  union SU { short8 v; unsigned int u[4]; };

#pragma unroll
  for (int jj = 0; jj < 8; ++jj) {
    const float* fj = &Fm[(w*8 + jj)*68 + quad*8];
    float4 j0 = *(const float4*)(fj);
    float4 j1 = *(const float4*)(fj + 4);
    float4 j2 = *(const float4*)(fj + 32);
    float4 j3 = *(const float4*)(fj + 36);
#pragma unroll
    for (int kb2 = 0; kb2 < 2; ++kb2) {
      float4 k0 = fkv[kb2][0], k1 = fkv[kb2][1];
      float4 k2v = fkv[kb2][2], k3v = fkv[kb2][3];
      SU A0, A1;
      A0.u[0] = pk2(j0.x*k0.x, j0.y*k0.y);
      A0.u[1] = pk2(j0.z*k0.z, j0.w*k0.w);
      A0.u[2] = pk2(j1.x*k1.x, j1.y*k1.y);
      A0.u[3] = pk2(j1.z*k1.z, j1.w*k1.w);
      A1.u[0] = pk2(j2.x*k2v.x, j2.y*k2v.y);
      A1.u[1] = pk2(j2.z*k2v.z, j2.w*k2v.w);
      A1.u[2] = pk2(j3.x*k3v.x, j3.y*k3v.y);
      A1.u[3] = pk2(j3.z*k3v.z, j3.w*k3v.w);
      f32x4 ac[4];
#pragma unroll
      for (int n = 0; n < 4; ++n) {
        f32x4 z = {0.f, 0.f, 0.f, 0.f};
        ac[n] = mfma_bf16(A1.v, Bq[n][1], mfma_bf16(A0.v, Bq[n][0], z));
      }
#pragma unroll
      for (int n = 0; n < 4; ++n)
#pragma unroll
        for (int r = 0; r < 4; ++r) {
          float v = ac[n][r] + kcv[kb2][r][n] + jcq[jj][n];
          sum[n] += fmaxf(v, 0.f);
        }
    }
  }

#pragma unroll
  for (int n = 0; n < 4; ++n) {
    float v = sum[n];
    v += __shfl_xor(v, 16, 64);
    v += __shfl_xor(v, 32, 64);
    if (l < 16) RED[w*64 + n*16 + l] = v;
  }
  __syncthreads();
  if (t < 64) {
    float tot = RED[t] + RED[64 + t] + RED[128 + t] + RED[192 + t];
    x8p[(b*32 + i)*64 + t] = tot;            // non-atomic partial
  }
}

// ---------------- k6: reduce x8p over i; x9 = relu(x8/K^3); out = x9 @ out_w.T + out_b ----------------
__global__ __launch_bounds__(64) void k6_out(const float* __restrict__ x8p,
    const float* __restrict__ ow, const float* __restrict__ ob,
    float* __restrict__ out) {
  const int bb = blockIdx.x, t = threadIdx.x;
  float a = 0.f;
#pragma unroll
  for (int i = 0; i < 32; ++i) a += x8p[(bb*32 + i)*64 + t];
  float v = fmaxf(a * (1.f/32768.f), 0.f) * ow[t];
#pragma unroll
  for (int off = 32; off > 0; off >>= 1) v += __shfl_down(v, off, 64);
  if (t == 0) out[bb] = v + ob[0];
}

extern "C" void kernel_launch(void* const* d_in, const int* in_sizes, int n_in,
                              void* d_out, int out_size, void* d_ws, size_t ws_size,
                              hipStream_t stream) {
  const float* x   = (const float*)d_in[0];
  const float* c1w = (const float*)d_in[1];
  const float* c1b = (const float*)d_in[2];
  const float* c2w = (const float*)d_in[3];
  const float* c2b = (const float*)d_in[4];
  const float* fcw = (const float*)d_in[5];
  const float* fcb = (const float*)d_in[6];
  const float* eqw = (const float*)d_in[7];
  const float* eqb = (const float*)d_in[8];
  const float* ow  = (const float*)d_in[9];
  const float* ob  = (const float*)d_in[10];
  float* out = (float*)d_out;

  float* feat = (float*)d_ws;             // 512*64 f32
  float* x8p  = feat + 32768;             // 512*64 f32
  float* W7t  = x8p + 32768;              // 4096 f32
  short* Wtb  = (short*)(W7t + 4096);     // 7*4096 bf16
  short* w2p  = Wtb + 28672;              // 18432 bf16
  short* fcwt = w2p + 18432;              // 3136*64 bf16, [k][e]
  float* s    = (float*)(fcwt + 200704);  // 1024 f32
  float* t7c  = s + 1024;                 // 1024 f32
  (void)in_sizes; (void)n_in; (void)out_size; (void)ws_size;

  hipLaunchKernelGGL(k0_prep, dim3(25), dim3(256), 0, stream,
                     eqw, c2w, fcw, W7t, Wtb, w2p, fcwt);
  hipLaunchKernelGGL(kA_conv, dim3(512), dim3(256), 0, stream,
                     x, c1w, c1b, w2p, c2b, fcwt, fcb, feat);
  hipLaunchKernelGGL(k4b,     dim3(16),  dim3(256), 0, stream,
                     feat, W7t, eqb, s, t7c);
  hipLaunchKernelGGL(k5_mfma, dim3(32, 16), dim3(256), 0, stream,
                     feat, s, Wtb, t7c, x8p);
  hipLaunchKernelGGL(k6_out,  dim3(16),  dim3(64),  0, stream, x8p, ow, ob, out);
}

// Round 7
// 126.904 us; speedup vs baseline: 1.2501x; 1.0126x over previous
//
#include <hip/hip_runtime.h>
#include <hip/hip_bf16.h>

// B=16, K=32, H=W=28, HID=OUT=64, NOPS=8
// ws: feat f32[512*64] | x8p f32[512*64] | W7t f32[4096] | Wtb bf16[7*4096] ([m][e][d])
//     | w2p bf16[18432] | fcwt bf16[3136*64] ([k][e]) | s f32[1024] | t7c f32[1024]

typedef __attribute__((ext_vector_type(8))) short short8;
typedef __attribute__((ext_vector_type(4))) float f32x4;

__device__ __forceinline__ f32x4 mfma_bf16(short8 a, short8 b, f32x4 c) {
  return __builtin_amdgcn_mfma_f32_16x16x32_bf16(a, b, c, 0, 0, 0);
}

// float -> bf16 bits, round-to-nearest-even (finite inputs only)
__device__ __forceinline__ unsigned short f2bs(float f) {
  unsigned int u = __float_as_uint(f);
  unsigned int r = u + 0x7fffu + ((u >> 16) & 1u);
  return (unsigned short)(r >> 16);
}
// packed 2xfp32 -> 2xbf16 (v_cvt_pk_bf16_f32 on gfx950)
__device__ __forceinline__ unsigned int pk2(float x, float y) {
  union { __hip_bfloat162 h; unsigned int u; } cv;
  cv.h = __float22bfloat162_rn(make_float2(x, y));
  return cv.u;
}
// unpack 8 bf16 (16B) -> 8 f32
__device__ __forceinline__ void ub8(const short* p, float* f) {
  uint4 u = *(const uint4*)p;
  f[0] = __uint_as_float(u.x << 16); f[1] = __uint_as_float(u.x & 0xffff0000u);
  f[2] = __uint_as_float(u.y << 16); f[3] = __uint_as_float(u.y & 0xffff0000u);
  f[4] = __uint_as_float(u.z << 16); f[5] = __uint_as_float(u.z & 0xffff0000u);
  f[6] = __uint_as_float(u.w << 16); f[7] = __uint_as_float(u.w & 0xffff0000u);
}

// ---------------- k0: weight prep (eq_w, conv2 pack, FC transpose to [k][e] bf16) ----------------
__global__ __launch_bounds__(256) void k0_prep(const float* __restrict__ eqw,
    const float* __restrict__ w2, const float* __restrict__ fcw,
    float* __restrict__ W7t, short* __restrict__ Wtb,
    short* __restrict__ w2p, short* __restrict__ fcwt) {
  const int b = blockIdx.x, t = threadIdx.x;
  if (b < 8) {                 // eq_w (d,e,m) -> W7t f32 / Wtb bf16, [e][d]
    const int m = b;
    for (int idx = t; idx < 4096; idx += 256) {
      int e = idx >> 6, d = idx & 63;
      float v = eqw[d*512 + e*8 + m];
      if (m == 7) W7t[idx] = v;
      else        Wtb[m*4096 + idx] = (short)f2bs(v);
    }
  } else if (b == 8) {
    // conv2 weights -> B-fragment layout: w2p[((dd*4+quad)*64 + cout)*8 + s]
    for (int idx = t; idx < 18432; idx += 256) {
      int s2 = idx & 7, c = (idx >> 3) & 63, quad = (idx >> 9) & 3, dd = idx >> 11;
      w2p[idx] = (short)f2bs(w2[c*288 + (quad*8 + s2)*9 + dd]);
    }
  } else {                     // fc_w [e][k] f32 -> fcwt [k][e] bf16 (coalesced writes)
    int base = (b - 9)*12544 + t;
    for (int q = 0; q < 49; ++q) {
      int idx = base + q*256;          // idx = k*64 + e
      int k = idx >> 6, e = idx & 63;
      fcwt[idx] = (short)f2bs(fcw[e*3136 + k]);
    }
  }
}

// ---------------- kA: conv1+pool -> LDS -> conv2(MFMA)+pool -> h2f(LDS) -> coalesced FC -> feat ----------------
__global__ __launch_bounds__(256, 2) void kA_conv(const float* __restrict__ x,
    const float* __restrict__ w1, const float* __restrict__ b1,
    const short* __restrict__ w2p, const float* __restrict__ b2,
    const short* __restrict__ fcwt, const float* __restrict__ fcb,
    float* __restrict__ feat) {
  const int n = blockIdx.x, t = threadIdx.x;
  __shared__ float si[30*30];
  __shared__ float sw[32*9];
  __shared__ float sb[32];
  __shared__ __align__(16) short inT[16*18*40];  // [yy][xx][cin stride 40]
  __shared__ __align__(16) float h2f[3136];      // pooled conv2 out, [c*49 + y*7 + x], f32
  __shared__ float sf4[256];                     // FC partials [w][e]
  const int wv = t >> 6, l = t & 63, quad = l >> 4, col = l & 15;

  // conv2 B fragments: pre-packed by k0, 9 coalesced 16B loads (R2-proven, VGPR-light)
  const int c_out = wv*16 + col;
  short8 Bq[9];
  {
    const short8* wp = (const short8*)w2p + quad*64 + c_out;
#pragma unroll
    for (int dd = 0; dd < 9; ++dd) Bq[dd] = wp[dd*256];
  }
  const float bb2 = b2[c_out];

  for (int idx = t; idx < 900; idx += 256) si[idx] = 0.f;
  {
    unsigned int* zp = (unsigned int*)inT;
    for (int idx = t; idx < 5760; idx += 256) zp[idx] = 0u;
  }
  for (int idx = t; idx < 288; idx += 256) sw[idx] = w1[idx];
  if (t < 32) sb[t] = b1[t];
  __syncthreads();
  for (int idx = t; idx < 784; idx += 256) {
    int y = idx / 28, xx = idx - y*28;
    si[(y+1)*30 + xx + 1] = x[n*784 + idx];
  }
  __syncthreads();

  // conv1 + relu + maxpool, 4 channels per thread, write bf16 into inT
  {
    const int cg = t & 7;
    float wreg[4][9], breg[4];
#pragma unroll
    for (int cc = 0; cc < 4; ++cc) {
      breg[cc] = sb[cg*4 + cc];
#pragma unroll
      for (int q = 0; q < 9; ++q) wreg[cc][q] = sw[(cg*4 + cc)*9 + q];
    }
    for (int idx = t; idx < 1568; idx += 256) {
      int pos = idx >> 3;
      int py = pos / 14, px = pos - py*14;
      float pt[4][4];
#pragma unroll
      for (int r = 0; r < 4; ++r)
#pragma unroll
        for (int q = 0; q < 4; ++q)
          pt[r][q] = si[(2*py + r)*30 + 2*px + q];
      float res[4];
#pragma unroll
      for (int cc = 0; cc < 4; ++cc) {
        float best = 0.f;
#pragma unroll
        for (int a = 0; a < 2; ++a)
#pragma unroll
          for (int b3 = 0; b3 < 2; ++b3) {
            float v = breg[cc]
              + wreg[cc][0]*pt[a+0][b3+0] + wreg[cc][1]*pt[a+0][b3+1] + wreg[cc][2]*pt[a+0][b3+2]
              + wreg[cc][3]*pt[a+1][b3+0] + wreg[cc][4]*pt[a+1][b3+1] + wreg[cc][5]*pt[a+1][b3+2]
              + wreg[cc][6]*pt[a+2][b3+0] + wreg[cc][7]*pt[a+2][b3+1] + wreg[cc][8]*pt[a+2][b3+2];
            best = fmaxf(best, v);
          }
        res[cc] = best;
      }
      uint2 pkd;
      pkd.x = pk2(res[0], res[1]);
      pkd.y = pk2(res[2], res[3]);
      *(uint2*)&inT[(py+1)*720 + (px+1)*40 + cg*4] = pkd;
    }
  }
  __syncthreads();

  // conv2 via MFMA + maxpool -> h2f (LDS, f32). Wave wv produces channels [16w,16w+16).
  for (int p = 0; p < 7; ++p) {
    short8 Ar[4][3];
#pragma unroll
    for (int rr = 0; rr < 4; ++rr)
#pragma unroll
      for (int dx = 0; dx < 3; ++dx)
        Ar[rr][dx] = *(const short8*)&inT[(2*p + rr)*720 + (col + dx)*40 + quad*8];
    f32x4 a0 = {0.f,0.f,0.f,0.f}, a1 = {0.f,0.f,0.f,0.f};
#pragma unroll
    for (int dy = 0; dy < 3; ++dy)
#pragma unroll
      for (int dx = 0; dx < 3; ++dx) {
        a0 = mfma_bf16(Ar[dy][dx],     Bq[dy*3 + dx], a0);
        a1 = mfma_bf16(Ar[dy + 1][dx], Bq[dy*3 + dx], a1);
      }
#pragma unroll
    for (int a = 0; a < 2; ++a) {
      int px = quad*2 + a;
      if (px < 7) {
        float m0 = fmaxf(fmaxf(a0[2*a], a0[2*a + 1]), fmaxf(a1[2*a], a1[2*a + 1]));
        h2f[c_out*49 + p*7 + px] = fmaxf(m0 + bb2, 0.f);
      }
    }
  }
  // Coalesced fused FC 3136->64 with fcwt [k][e] bf16.
  // Lane l: g = l>>3 (k-offset within octet), s = l&7 (e-octet). Wave wv covers
  // k in [784wv, 784wv+784) == exactly the h2f channels it wrote (wave-local, no barrier).
  // Each wave-load = 1KB contiguous (16B/lane) -> fully coalesced L2 reads.
  {
    const int g = l >> 3, s = l & 7;
    const short* Wp = fcwt + (wv*784 + g)*64 + s*8;
    const float* Hp = h2f + wv*784 + g;
    float acc[8] = {0.f,0.f,0.f,0.f,0.f,0.f,0.f,0.f};
#pragma unroll 7
    for (int j = 0; j < 98; ++j) {
      float wf[8]; ub8(Wp + j*512, wf);
      float hk = Hp[j*8];
#pragma unroll
      for (int q = 0; q < 8; ++q) acc[q] += wf[q] * hk;
    }
#pragma unroll
    for (int q = 0; q < 8; ++q) {
      acc[q] += __shfl_xor(acc[q], 8, 64);
      acc[q] += __shfl_xor(acc[q], 16, 64);
      acc[q] += __shfl_xor(acc[q], 32, 64);
    }
    if (g == 0) {
#pragma unroll
      for (int q = 0; q < 8; ++q) sf4[wv*64 + s*8 + q] = acc[q];
    }
  }
  __syncthreads();
  if (t < 64) {
    float v = sf4[t] + sf4[64 + t] + sf4[128 + t] + sf4[192 + t] + fcb[t];
    feat[n*64 + t] = fmaxf(v, 0.f);
  }
}

// ---------------- k4b: s = mean_K(feat), t7c = (s^3)@W7 + eqb ----------------
__global__ __launch_bounds__(256) void k4b(const float* __restrict__ feat,
    const float* __restrict__ W7t, const float* __restrict__ eqb,
    float* __restrict__ s, float* __restrict__ t7c) {
  __shared__ __align__(16) float sf[2048];
  __shared__ float ss[64];
  const int b = blockIdx.x, t = threadIdx.x;
  for (int v4 = t; v4 < 512; v4 += 256)
    *(float4*)&sf[v4*4] = *(const float4*)&feat[b*2048 + v4*4];
  __syncthreads();
  if (t < 64) {
    float a = 0.f;
#pragma unroll
    for (int r = 0; r < 32; ++r) a += sf[r*64 + t];
    a *= (1.f/32.f);
    s[b*64 + t] = a;
    ss[t] = a;
  }
  __syncthreads();
  if (t < 64) {
    const float* W7 = W7t + t*64;   // [e=t][d]
    float t7 = 0.f;
    for (int d = 0; d < 64; ++d) {
      float sv = ss[d];
      t7 += sv*sv*sv * W7[d];
    }
    t7c[b*64 + t] = t7 + eqb[t];
  }
}

// ---------------- k5: fused equivariant layer via bf16 MFMA -> x8p partials ----------------
// UNCAPPED launch bounds: the ~180-reg live set must NOT spill (rounds 2/6: a 128-VGPR
// cap produces ~40+ MB of scratch traffic and ~43 µs). Grid 512 on 256 CUs = 2 blocks/CU
// regardless (LDS-bound at 61 KB), so no occupancy is lost by uncapping.
__global__ __launch_bounds__(256) void k5_mfma(const float* __restrict__ feat,
    const float* __restrict__ s_, const short* __restrict__ Wtb,
    const float* __restrict__ t7c, float* __restrict__ x8p) {
  __shared__ __align__(16) float Fm[32*68];
  __shared__ __align__(16) float FI[64];
  __shared__ __align__(16) float SV[64];
  __shared__ __align__(16) float C0[64];
  __shared__ float C0P[128];
  __shared__ float KCf[32*68];
  __shared__ float JCf[32*68];
  __shared__ float RED[256];
  __shared__ __align__(16) short Fb[32*72];
  __shared__ __align__(16) short QPb[64*72];
  __shared__ __align__(16) short G2b[64*72];
  __shared__ __align__(16) short G3b[64*72];

  const int i = blockIdx.x, b = blockIdx.y, t = threadIdx.x;
  const int w = t >> 6, l = t & 63, quad = l >> 4, col = l & 15;

  for (int idx = t; idx < 2048; idx += 256) {
    int r = idx >> 6, d = idx & 63;
    float v = feat[b*2048 + idx];
    Fm[r*68 + d] = v;
    Fb[r*72 + d] = (short)f2bs(v);
  }
  if (t < 64) { FI[t] = feat[b*2048 + i*64 + t]; SV[t] = s_[b*64 + t]; }
  __syncthreads();

  // P0b: QPb = fi*W0 + s*W1 ; G2b = s*(fi*W2 + s*W4) ; G3b = s*(fi*W3 + s*W5)  (bf16 weights)
  {
    const int e = t >> 2, dbase = (t & 3) * 16;
#pragma unroll
    for (int h = 0; h < 2; ++h) {
      int off = dbase + h*8;
      float w0[8], w1[8], w2[8], w3[8], w4[8], w5[8];
      ub8(&Wtb[0*4096 + e*64 + off], w0);
      ub8(&Wtb[1*4096 + e*64 + off], w1);
      ub8(&Wtb[2*4096 + e*64 + off], w2);
      ub8(&Wtb[3*4096 + e*64 + off], w3);
      ub8(&Wtb[4*4096 + e*64 + off], w4);
      ub8(&Wtb[5*4096 + e*64 + off], w5);
      uint4 qv, g2v, g3v;
      unsigned int* qp = &qv.x;
      unsigned int* g2p = &g2v.x;
      unsigned int* g3p = &g3v.x;
#pragma unroll
      for (int j = 0; j < 4; ++j) {
        float fi0 = FI[off + 2*j],     fi1 = FI[off + 2*j + 1];
        float s0  = SV[off + 2*j],     s1  = SV[off + 2*j + 1];
        float q0 = fi0*w0[2*j]   + s0*w1[2*j];
        float q1 = fi1*w0[2*j+1] + s1*w1[2*j+1];
        float a0 = s0*(fi0*w2[2*j]   + s0*w4[2*j]);
        float a1 = s1*(fi1*w2[2*j+1] + s1*w4[2*j+1]);
        float c0 = s0*(fi0*w3[2*j]   + s0*w5[2*j]);
        float c1 = s1*(fi1*w3[2*j+1] + s1*w5[2*j+1]);
        qp[j]  = pk2(q0, q1);
        g2p[j] = pk2(a0, a1);
        g3p[j] = pk2(c0, c1);
      }
      *(uint4*)&QPb[e*72 + off] = qv;
      *(uint4*)&G2b[e*72 + off] = g2v;
      *(uint4*)&G3b[e*72 + off] = g3v;
    }
  }
  if (t < 128) {
    int e = t & 63, dh = t >> 6;
    const short* W6 = Wtb + 6*4096 + e*64 + dh*32;
    float a = 0.f;
#pragma unroll
    for (int g = 0; g < 4; ++g) {
      float wf[8];
      ub8(&W6[g*8], wf);
#pragma unroll
      for (int dd = 0; dd < 8; ++dd) {
        int d = dh*32 + g*8 + dd;
        float sd = SV[d];
        a += sd*sd*FI[d]*wf[dd];
      }
    }
    C0P[dh*64 + e] = a;
  }
  __syncthreads();

  if (w < 2) {
    const short* G = w ? G3b : G2b;
    float* DST = w ? JCf : KCf;
    short8 Bf[4][2];
#pragma unroll
    for (int n = 0; n < 4; ++n)
#pragma unroll
      for (int s2 = 0; s2 < 2; ++s2)
        Bf[n][s2] = *(const short8*)&G[(n*16 + col)*72 + s2*32 + quad*8];
#pragma unroll
    for (int m = 0; m < 2; ++m) {
      short8 A0 = *(const short8*)&Fb[(m*16 + col)*72 + quad*8];
      short8 A1 = *(const short8*)&Fb[(m*16 + col)*72 + 32 + quad*8];
#pragma unroll
      for (int n = 0; n < 4; ++n) {
        f32x4 z = {0.f, 0.f, 0.f, 0.f};
        f32x4 ac = mfma_bf16(A1, Bf[n][1], mfma_bf16(A0, Bf[n][0], z));
#pragma unroll
        for (int r = 0; r < 4; ++r)
          DST[(m*16 + quad*4 + r)*68 + n*16 + col] = ac[r];
      }
    }
  } else if (w == 2) {
    C0[l] = C0P[l] + C0P[64 + l] + t7c[b*64 + l];
  }
  __syncthreads();

  float kcv[2][4][4];
#pragma unroll
  for (int kb2 = 0; kb2 < 2; ++kb2)
#pragma unroll
    for (int r = 0; r < 4; ++r)
#pragma unroll
      for (int n = 0; n < 4; ++n)
        kcv[kb2][r][n] = KCf[(kb2*16 + quad*4 + r)*68 + n*16 + col];
  short8 Bq[4][2];
#pragma unroll
  for (int n = 0; n < 4; ++n)
#pragma unroll
    for (int s2 = 0; s2 < 2; ++s2)
      Bq[n][s2] = *(const short8*)&QPb[(n*16 + col)*72 + s2*32 + quad*8];

  float4 fkv[2][4];
#pragma unroll
  for (int kb2 = 0; kb2 < 2; ++kb2) {
    const float* fk = &Fm[(kb2*16 + col)*68 + quad*8];
    fkv[kb2][0] = *(const float4*)(fk);
    fkv[kb2][1] = *(const float4*)(fk + 4);
    fkv[kb2][2] = *(const float4*)(fk + 32);
    fkv[kb2][3] = *(const float4*)(fk + 36);
  }

  float sum[4] = {0.f, 0.f, 0.f, 0.f};
  union SU { short8 v; unsigned int u[4]; };

#pragma unroll
  for (int jj = 0; jj < 8; ++jj) {
    // jcq re-read per-jj from LDS (keeps peak VGPR pressure under the no-spill line)
    float jcq[4];
#pragma unroll
    for (int n = 0; n < 4; ++n)
      jcq[n] = JCf[(w*8 + jj)*68 + n*16 + col] + C0[n*16 + col];
    const float* fj = &Fm[(w*8 + jj)*68 + quad*8];
    float4 j0 = *(const float4*)(fj);
    float4 j1 = *(const float4*)(fj + 4);
    float4 j2 = *(const float4*)(fj + 32);
    float4 j3 = *(const float4*)(fj + 36);
#pragma unroll
    for (int kb2 = 0; kb2 < 2; ++kb2) {
      float4 k0 = fkv[kb2][0], k1 = fkv[kb2][1];
      float4 k2v = fkv[kb2][2], k3v = fkv[kb2][3];
      SU A0, A1;
      A0.u[0] = pk2(j0.x*k0.x, j0.y*k0.y);
      A0.u[1] = pk2(j0.z*k0.z, j0.w*k0.w);
      A0.u[2] = pk2(j1.x*k1.x, j1.y*k1.y);
      A0.u[3] = pk2(j1.z*k1.z, j1.w*k1.w);
      A1.u[0] = pk2(j2.x*k2v.x, j2.y*k2v.y);
      A1.u[1] = pk2(j2.z*k2v.z, j2.w*k2v.w);
      A1.u[2] = pk2(j3.x*k3v.x, j3.y*k3v.y);
      A1.u[3] = pk2(j3.z*k3v.z, j3.w*k3v.w);
      f32x4 ac[4];
#pragma unroll
      for (int n = 0; n < 4; ++n) {
        f32x4 z = {0.f, 0.f, 0.f, 0.f};
        ac[n] = mfma_bf16(A1.v, Bq[n][1], mfma_bf16(A0.v, Bq[n][0], z));
      }
#pragma unroll
      for (int n = 0; n < 4; ++n)
#pragma unroll
        for (int r = 0; r < 4; ++r) {
          float v = ac[n][r] + kcv[kb2][r][n] + jcq[n];
          sum[n] += fmaxf(v, 0.f);
        }
    }
  }

#pragma unroll
  for (int n = 0; n < 4; ++n) {
    float v = sum[n];
    v += __shfl_xor(v, 16, 64);
    v += __shfl_xor(v, 32, 64);
    if (l < 16) RED[w*64 + n*16 + l] = v;
  }
  __syncthreads();
  if (t < 64) {
    float tot = RED[t] + RED[64 + t] + RED[128 + t] + RED[192 + t];
    x8p[(b*32 + i)*64 + t] = tot;            // non-atomic partial
  }
}

// ---------------- k6: reduce x8p over i; x9 = relu(x8/K^3); out = x9 @ out_w.T + out_b ----------------
__global__ __launch_bounds__(64) void k6_out(const float* __restrict__ x8p,
    const float* __restrict__ ow, const float* __restrict__ ob,
    float* __restrict__ out) {
  const int bb = blockIdx.x, t = threadIdx.x;
  float a = 0.f;
#pragma unroll
  for (int i = 0; i < 32; ++i) a += x8p[(bb*32 + i)*64 + t];
  float v = fmaxf(a * (1.f/32768.f), 0.f) * ow[t];
#pragma unroll
  for (int off = 32; off > 0; off >>= 1) v += __shfl_down(v, off, 64);
  if (t == 0) out[bb] = v + ob[0];
}

extern "C" void kernel_launch(void* const* d_in, const int* in_sizes, int n_in,
                              void* d_out, int out_size, void* d_ws, size_t ws_size,
                              hipStream_t stream) {
  const float* x   = (const float*)d_in[0];
  const float* c1w = (const float*)d_in[1];
  const float* c1b = (const float*)d_in[2];
  const float* c2w = (const float*)d_in[3];
  const float* c2b = (const float*)d_in[4];
  const float* fcw = (const float*)d_in[5];
  const float* fcb = (const float*)d_in[6];
  const float* eqw = (const float*)d_in[7];
  const float* eqb = (const float*)d_in[8];
  const float* ow  = (const float*)d_in[9];
  const float* ob  = (const float*)d_in[10];
  float* out = (float*)d_out;

  float* feat = (float*)d_ws;             // 512*64 f32
  float* x8p  = feat + 32768;             // 512*64 f32
  float* W7t  = x8p + 32768;              // 4096 f32
  short* Wtb  = (short*)(W7t + 4096);     // 7*4096 bf16
  short* w2p  = Wtb + 28672;              // 18432 bf16
  short* fcwt = w2p + 18432;              // 3136*64 bf16, [k][e]
  float* s    = (float*)(fcwt + 200704);  // 1024 f32
  float* t7c  = s + 1024;                 // 1024 f32
  (void)in_sizes; (void)n_in; (void)out_size; (void)ws_size;

  hipLaunchKernelGGL(k0_prep, dim3(25), dim3(256), 0, stream,
                     eqw, c2w, fcw, W7t, Wtb, w2p, fcwt);
  hipLaunchKernelGGL(kA_conv, dim3(512), dim3(256), 0, stream,
                     x, c1w, c1b, w2p, c2b, fcwt, fcb, feat);
  hipLaunchKernelGGL(k4b,     dim3(16),  dim3(256), 0, stream,
                     feat, W7t, eqb, s, t7c);
  hipLaunchKernelGGL(k5_mfma, dim3(32, 16), dim3(256), 0, stream,
                     feat, s, Wtb, t7c, x8p);
  hipLaunchKernelGGL(k6_out,  dim3(16),  dim3(64),  0, stream, x8p, ow, ob, out);
}

// Round 8
// 125.923 us; speedup vs baseline: 1.2599x; 1.0078x over previous
//
#include <hip/hip_runtime.h>
#include <hip/hip_bf16.h>

// B=16, K=32, H=W=28, HID=OUT=64, NOPS=8
// ws: feat f32[512*64] | x8p f32[512*64] | W7t f32[4096] | Wtb bf16[7*4096] ([m][e][d])
//     | w2p bf16[18432] | fcwt bf16[3136*64] ([k][e]) | s f32[1024] | t7c f32[1024]

typedef __attribute__((ext_vector_type(8))) short short8;
typedef __attribute__((ext_vector_type(4))) float f32x4;

__device__ __forceinline__ f32x4 mfma_bf16(short8 a, short8 b, f32x4 c) {
  return __builtin_amdgcn_mfma_f32_16x16x32_bf16(a, b, c, 0, 0, 0);
}

// float -> bf16 bits, round-to-nearest-even (finite inputs only)
__device__ __forceinline__ unsigned short f2bs(float f) {
  unsigned int u = __float_as_uint(f);
  unsigned int r = u + 0x7fffu + ((u >> 16) & 1u);
  return (unsigned short)(r >> 16);
}
// packed 2xfp32 -> 2xbf16 (v_cvt_pk_bf16_f32 on gfx950)
__device__ __forceinline__ unsigned int pk2(float x, float y) {
  union { __hip_bfloat162 h; unsigned int u; } cv;
  cv.h = __float22bfloat162_rn(make_float2(x, y));
  return cv.u;
}
// unpack 8 bf16 (16B) -> 8 f32
__device__ __forceinline__ void ub8(const short* p, float* f) {
  uint4 u = *(const uint4*)p;
  f[0] = __uint_as_float(u.x << 16); f[1] = __uint_as_float(u.x & 0xffff0000u);
  f[2] = __uint_as_float(u.y << 16); f[3] = __uint_as_float(u.y & 0xffff0000u);
  f[4] = __uint_as_float(u.z << 16); f[5] = __uint_as_float(u.z & 0xffff0000u);
  f[6] = __uint_as_float(u.w << 16); f[7] = __uint_as_float(u.w & 0xffff0000u);
}

// ---------------- k0: weight prep (eq_w, conv2 pack, FC transpose to [k][e] bf16) ----------------
__global__ __launch_bounds__(256) void k0_prep(const float* __restrict__ eqw,
    const float* __restrict__ w2, const float* __restrict__ fcw,
    float* __restrict__ W7t, short* __restrict__ Wtb,
    short* __restrict__ w2p, short* __restrict__ fcwt) {
  const int b = blockIdx.x, t = threadIdx.x;
  if (b < 8) {                 // eq_w (d,e,m) -> W7t f32 / Wtb bf16, [e][d]
    const int m = b;
    for (int idx = t; idx < 4096; idx += 256) {
      int e = idx >> 6, d = idx & 63;
      float v = eqw[d*512 + e*8 + m];
      if (m == 7) W7t[idx] = v;
      else        Wtb[m*4096 + idx] = (short)f2bs(v);
    }
  } else if (b == 8) {
    // conv2 weights -> B-fragment layout: w2p[((dd*4+quad)*64 + cout)*8 + s]
    for (int idx = t; idx < 18432; idx += 256) {
      int s2 = idx & 7, c = (idx >> 3) & 63, quad = (idx >> 9) & 3, dd = idx >> 11;
      w2p[idx] = (short)f2bs(w2[c*288 + (quad*8 + s2)*9 + dd]);
    }
  } else {                     // fc_w [e][k] f32 -> fcwt [k][e] bf16 (coalesced writes)
    int base = (b - 9)*12544 + t;
    for (int q = 0; q < 49; ++q) {
      int idx = base + q*256;          // idx = k*64 + e
      int k = idx >> 6, e = idx & 63;
      fcwt[idx] = (short)f2bs(fcw[e*3136 + k]);
    }
  }
}

// ---------------- kA: conv1+pool -> LDS -> conv2(MFMA)+pool -> h2f(LDS) -> coalesced FC -> feat ----------------
__global__ __launch_bounds__(256, 2) void kA_conv(const float* __restrict__ x,
    const float* __restrict__ w1, const float* __restrict__ b1,
    const short* __restrict__ w2p, const float* __restrict__ b2,
    const short* __restrict__ fcwt, const float* __restrict__ fcb,
    float* __restrict__ feat) {
  const int n = blockIdx.x, t = threadIdx.x;
  __shared__ float si[30*30];
  __shared__ float sw[32*9];
  __shared__ float sb[32];
  __shared__ __align__(16) short inT[16*18*40];  // [yy][xx][cin stride 40]
  __shared__ __align__(16) float h2f[3136];      // pooled conv2 out, [c*49 + y*7 + x], f32
  __shared__ float sf4[256];                     // FC partials [w][e]
  const int wv = t >> 6, l = t & 63, quad = l >> 4, col = l & 15;

  // conv2 B fragments: pre-packed by k0, 9 coalesced 16B loads (R2-proven, VGPR-light)
  const int c_out = wv*16 + col;
  short8 Bq[9];
  {
    const short8* wp = (const short8*)w2p + quad*64 + c_out;
#pragma unroll
    for (int dd = 0; dd < 9; ++dd) Bq[dd] = wp[dd*256];
  }
  const float bb2 = b2[c_out];

  for (int idx = t; idx < 900; idx += 256) si[idx] = 0.f;
  {
    unsigned int* zp = (unsigned int*)inT;
    for (int idx = t; idx < 5760; idx += 256) zp[idx] = 0u;
  }
  for (int idx = t; idx < 288; idx += 256) sw[idx] = w1[idx];
  if (t < 32) sb[t] = b1[t];
  __syncthreads();
  for (int idx = t; idx < 784; idx += 256) {
    int y = idx / 28, xx = idx - y*28;
    si[(y+1)*30 + xx + 1] = x[n*784 + idx];
  }
  __syncthreads();

  // conv1 + relu + maxpool, 4 channels per thread, write bf16 into inT
  {
    const int cg = t & 7;
    float wreg[4][9], breg[4];
#pragma unroll
    for (int cc = 0; cc < 4; ++cc) {
      breg[cc] = sb[cg*4 + cc];
#pragma unroll
      for (int q = 0; q < 9; ++q) wreg[cc][q] = sw[(cg*4 + cc)*9 + q];
    }
    for (int idx = t; idx < 1568; idx += 256) {
      int pos = idx >> 3;
      int py = pos / 14, px = pos - py*14;
      float pt[4][4];
#pragma unroll
      for (int r = 0; r < 4; ++r)
#pragma unroll
        for (int q = 0; q < 4; ++q)
          pt[r][q] = si[(2*py + r)*30 + 2*px + q];
      float res[4];
#pragma unroll
      for (int cc = 0; cc < 4; ++cc) {
        float best = 0.f;
#pragma unroll
        for (int a = 0; a < 2; ++a)
#pragma unroll
          for (int b3 = 0; b3 < 2; ++b3) {
            float v = breg[cc]
              + wreg[cc][0]*pt[a+0][b3+0] + wreg[cc][1]*pt[a+0][b3+1] + wreg[cc][2]*pt[a+0][b3+2]
              + wreg[cc][3]*pt[a+1][b3+0] + wreg[cc][4]*pt[a+1][b3+1] + wreg[cc][5]*pt[a+1][b3+2]
              + wreg[cc][6]*pt[a+2][b3+0] + wreg[cc][7]*pt[a+2][b3+1] + wreg[cc][8]*pt[a+2][b3+2];
            best = fmaxf(best, v);
          }
        res[cc] = best;
      }
      uint2 pkd;
      pkd.x = pk2(res[0], res[1]);
      pkd.y = pk2(res[2], res[3]);
      *(uint2*)&inT[(py+1)*720 + (px+1)*40 + cg*4] = pkd;
    }
  }
  __syncthreads();

  // conv2 via MFMA + maxpool -> h2f (LDS, f32). Wave wv produces channels [16w,16w+16).
  for (int p = 0; p < 7; ++p) {
    short8 Ar[4][3];
#pragma unroll
    for (int rr = 0; rr < 4; ++rr)
#pragma unroll
      for (int dx = 0; dx < 3; ++dx)
        Ar[rr][dx] = *(const short8*)&inT[(2*p + rr)*720 + (col + dx)*40 + quad*8];
    f32x4 a0 = {0.f,0.f,0.f,0.f}, a1 = {0.f,0.f,0.f,0.f};
#pragma unroll
    for (int dy = 0; dy < 3; ++dy)
#pragma unroll
      for (int dx = 0; dx < 3; ++dx) {
        a0 = mfma_bf16(Ar[dy][dx],     Bq[dy*3 + dx], a0);
        a1 = mfma_bf16(Ar[dy + 1][dx], Bq[dy*3 + dx], a1);
      }
#pragma unroll
    for (int a = 0; a < 2; ++a) {
      int px = quad*2 + a;
      if (px < 7) {
        float m0 = fmaxf(fmaxf(a0[2*a], a0[2*a + 1]), fmaxf(a1[2*a], a1[2*a + 1]));
        h2f[c_out*49 + p*7 + px] = fmaxf(m0 + bb2, 0.f);
      }
    }
  }
  // Coalesced fused FC 3136->64 with fcwt [k][e] bf16.
  // Lane l: g = l>>3 (k-offset within octet), s = l&7 (e-octet). Wave wv covers
  // k in [784wv, 784wv+784) == exactly the h2f channels it wrote (wave-local, no barrier).
  // Each wave-load = 1KB contiguous (16B/lane) -> fully coalesced L2 reads.
  {
    const int g = l >> 3, s = l & 7;
    const short* Wp = fcwt + (wv*784 + g)*64 + s*8;
    const float* Hp = h2f + wv*784 + g;
    float acc[8] = {0.f,0.f,0.f,0.f,0.f,0.f,0.f,0.f};
#pragma unroll 7
    for (int j = 0; j < 98; ++j) {
      float wf[8]; ub8(Wp + j*512, wf);
      float hk = Hp[j*8];
#pragma unroll
      for (int q = 0; q < 8; ++q) acc[q] += wf[q] * hk;
    }
#pragma unroll
    for (int q = 0; q < 8; ++q) {
      acc[q] += __shfl_xor(acc[q], 8, 64);
      acc[q] += __shfl_xor(acc[q], 16, 64);
      acc[q] += __shfl_xor(acc[q], 32, 64);
    }
    if (g == 0) {
#pragma unroll
      for (int q = 0; q < 8; ++q) sf4[wv*64 + s*8 + q] = acc[q];
    }
  }
  __syncthreads();
  if (t < 64) {
    float v = sf4[t] + sf4[64 + t] + sf4[128 + t] + sf4[192 + t] + fcb[t];
    feat[n*64 + t] = fmaxf(v, 0.f);
  }
}

// ---------------- k4b: s = mean_K(feat), t7c = (s^3)@W7 + eqb ----------------
__global__ __launch_bounds__(256) void k4b(const float* __restrict__ feat,
    const float* __restrict__ W7t, const float* __restrict__ eqb,
    float* __restrict__ s, float* __restrict__ t7c) {
  __shared__ __align__(16) float sf[2048];
  __shared__ float ss[64];
  const int b = blockIdx.x, t = threadIdx.x;
  for (int v4 = t; v4 < 512; v4 += 256)
    *(float4*)&sf[v4*4] = *(const float4*)&feat[b*2048 + v4*4];
  __syncthreads();
  if (t < 64) {
    float a = 0.f;
#pragma unroll
    for (int r = 0; r < 32; ++r) a += sf[r*64 + t];
    a *= (1.f/32.f);
    s[b*64 + t] = a;
    ss[t] = a;
  }
  __syncthreads();
  if (t < 64) {
    const float* W7 = W7t + t*64;   // [e=t][d]
    float t7 = 0.f;
    for (int d = 0; d < 64; ++d) {
      float sv = ss[d];
      t7 += sv*sv*sv * W7[d];
    }
    t7c[b*64 + t] = t7 + eqb[t];
  }
}

// ---------------- k5: fused equivariant layer via bf16 MFMA -> x8p partials ----------------
// R0-VERBATIM config: (256,2) cap + jcq[8][4] precompute. This exact body ran inside the
// 122.9 µs baseline without spilling; the R2/R6 spills appeared only when an in-block
// s/t7c prologue was added on top of the cap. k4b supplies s/t7c, keeping the prologue lean.
__global__ __launch_bounds__(256, 2) void k5_mfma(const float* __restrict__ feat,
    const float* __restrict__ s_, const short* __restrict__ Wtb,
    const float* __restrict__ t7c, float* __restrict__ x8p) {
  __shared__ __align__(16) float Fm[32*68];
  __shared__ __align__(16) float FI[64];
  __shared__ __align__(16) float SV[64];
  __shared__ __align__(16) float C0[64];
  __shared__ float C0P[128];
  __shared__ float KCf[32*68];
  __shared__ float JCf[32*68];
  __shared__ float RED[256];
  __shared__ __align__(16) short Fb[32*72];
  __shared__ __align__(16) short QPb[64*72];
  __shared__ __align__(16) short G2b[64*72];
  __shared__ __align__(16) short G3b[64*72];

  const int i = blockIdx.x, b = blockIdx.y, t = threadIdx.x;
  const int w = t >> 6, l = t & 63, quad = l >> 4, col = l & 15;

  for (int idx = t; idx < 2048; idx += 256) {
    int r = idx >> 6, d = idx & 63;
    float v = feat[b*2048 + idx];
    Fm[r*68 + d] = v;
    Fb[r*72 + d] = (short)f2bs(v);
  }
  if (t < 64) { FI[t] = feat[b*2048 + i*64 + t]; SV[t] = s_[b*64 + t]; }
  __syncthreads();

  // P0b: QPb = fi*W0 + s*W1 ; G2b = s*(fi*W2 + s*W4) ; G3b = s*(fi*W3 + s*W5)  (bf16 weights)
  {
    const int e = t >> 2, dbase = (t & 3) * 16;
#pragma unroll
    for (int h = 0; h < 2; ++h) {
      int off = dbase + h*8;
      float w0[8], w1[8], w2[8], w3[8], w4[8], w5[8];
      ub8(&Wtb[0*4096 + e*64 + off], w0);
      ub8(&Wtb[1*4096 + e*64 + off], w1);
      ub8(&Wtb[2*4096 + e*64 + off], w2);
      ub8(&Wtb[3*4096 + e*64 + off], w3);
      ub8(&Wtb[4*4096 + e*64 + off], w4);
      ub8(&Wtb[5*4096 + e*64 + off], w5);
      uint4 qv, g2v, g3v;
      unsigned int* qp = &qv.x;
      unsigned int* g2p = &g2v.x;
      unsigned int* g3p = &g3v.x;
#pragma unroll
      for (int j = 0; j < 4; ++j) {
        float fi0 = FI[off + 2*j],     fi1 = FI[off + 2*j + 1];
        float s0  = SV[off + 2*j],     s1  = SV[off + 2*j + 1];
        float q0 = fi0*w0[2*j]   + s0*w1[2*j];
        float q1 = fi1*w0[2*j+1] + s1*w1[2*j+1];
        float a0 = s0*(fi0*w2[2*j]   + s0*w4[2*j]);
        float a1 = s1*(fi1*w2[2*j+1] + s1*w4[2*j+1]);
        float c0 = s0*(fi0*w3[2*j]   + s0*w5[2*j]);
        float c1 = s1*(fi1*w3[2*j+1] + s1*w5[2*j+1]);
        qp[j]  = pk2(q0, q1);
        g2p[j] = pk2(a0, a1);
        g3p[j] = pk2(c0, c1);
      }
      *(uint4*)&QPb[e*72 + off] = qv;
      *(uint4*)&G2b[e*72 + off] = g2v;
      *(uint4*)&G3b[e*72 + off] = g3v;
    }
  }
  if (t < 128) {
    int e = t & 63, dh = t >> 6;
    const short* W6 = Wtb + 6*4096 + e*64 + dh*32;
    float a = 0.f;
#pragma unroll
    for (int g = 0; g < 4; ++g) {
      float wf[8];
      ub8(&W6[g*8], wf);
#pragma unroll
      for (int dd = 0; dd < 8; ++dd) {
        int d = dh*32 + g*8 + dd;
        float sd = SV[d];
        a += sd*sd*FI[d]*wf[dd];
      }
    }
    C0P[dh*64 + e] = a;
  }
  __syncthreads();

  if (w < 2) {
    const short* G = w ? G3b : G2b;
    float* DST = w ? JCf : KCf;
    short8 Bf[4][2];
#pragma unroll
    for (int n = 0; n < 4; ++n)
#pragma unroll
      for (int s2 = 0; s2 < 2; ++s2)
        Bf[n][s2] = *(const short8*)&G[(n*16 + col)*72 + s2*32 + quad*8];
#pragma unroll
    for (int m = 0; m < 2; ++m) {
      short8 A0 = *(const short8*)&Fb[(m*16 + col)*72 + quad*8];
      short8 A1 = *(const short8*)&Fb[(m*16 + col)*72 + 32 + quad*8];
#pragma unroll
      for (int n = 0; n < 4; ++n) {
        f32x4 z = {0.f, 0.f, 0.f, 0.f};
        f32x4 ac = mfma_bf16(A1, Bf[n][1], mfma_bf16(A0, Bf[n][0], z));
#pragma unroll
        for (int r = 0; r < 4; ++r)
          DST[(m*16 + quad*4 + r)*68 + n*16 + col] = ac[r];
      }
    }
  } else if (w == 2) {
    C0[l] = C0P[l] + C0P[64 + l] + t7c[b*64 + l];
  }
  __syncthreads();

  float c0v[4];
#pragma unroll
  for (int n = 0; n < 4; ++n) c0v[n] = C0[n*16 + col];
  float jcq[8][4];
#pragma unroll
  for (int jj = 0; jj < 8; ++jj)
#pragma unroll
    for (int n = 0; n < 4; ++n)
      jcq[jj][n] = JCf[(w*8 + jj)*68 + n*16 + col] + c0v[n];
  float kcv[2][4][4];
#pragma unroll
  for (int kb2 = 0; kb2 < 2; ++kb2)
#pragma unroll
    for (int r = 0; r < 4; ++r)
#pragma unroll
      for (int n = 0; n < 4; ++n)
        kcv[kb2][r][n] = KCf[(kb2*16 + quad*4 + r)*68 + n*16 + col];
  short8 Bq[4][2];
#pragma unroll
  for (int n = 0; n < 4; ++n)
#pragma unroll
    for (int s2 = 0; s2 < 2; ++s2)
      Bq[n][s2] = *(const short8*)&QPb[(n*16 + col)*72 + s2*32 + quad*8];

  float4 fkv[2][4];
#pragma unroll
  for (int kb2 = 0; kb2 < 2; ++kb2) {
    const float* fk = &Fm[(kb2*16 + col)*68 + quad*8];
    fkv[kb2][0] = *(const float4*)(fk);
    fkv[kb2][1] = *(const float4*)(fk + 4);
    fkv[kb2][2] = *(const float4*)(fk + 32);
    fkv[kb2][3] = *(const float4*)(fk + 36);
  }

  float sum[4] = {0.f, 0.f, 0.f, 0.f};
  union SU { short8 v; unsigned int u[4]; };

#pragma unroll
  for (int jj = 0; jj < 8; ++jj) {
    const float* fj = &Fm[(w*8 + jj)*68 + quad*8];
    float4 j0 = *(const float4*)(fj);
    float4 j1 = *(const float4*)(fj + 4);
    float4 j2 = *(const float4*)(fj + 32);
    float4 j3 = *(const float4*)(fj + 36);
#pragma unroll
    for (int kb2 = 0; kb2 < 2; ++kb2) {
      float4 k0 = fkv[kb2][0], k1 = fkv[kb2][1];
      float4 k2v = fkv[kb2][2], k3v = fkv[kb2][3];
      SU A0, A1;
      A0.u[0] = pk2(j0.x*k0.x, j0.y*k0.y);
      A0.u[1] = pk2(j0.z*k0.z, j0.w*k0.w);
      A0.u[2] = pk2(j1.x*k1.x, j1.y*k1.y);
      A0.u[3] = pk2(j1.z*k1.z, j1.w*k1.w);
      A1.u[0] = pk2(j2.x*k2v.x, j2.y*k2v.y);
      A1.u[1] = pk2(j2.z*k2v.z, j2.w*k2v.w);
      A1.u[2] = pk2(j3.x*k3v.x, j3.y*k3v.y);
      A1.u[3] = pk2(j3.z*k3v.z, j3.w*k3v.w);
      f32x4 ac[4];
#pragma unroll
      for (int n = 0; n < 4; ++n) {
        f32x4 z = {0.f, 0.f, 0.f, 0.f};
        ac[n] = mfma_bf16(A1.v, Bq[n][1], mfma_bf16(A0.v, Bq[n][0], z));
      }
#pragma unroll
      for (int n = 0; n < 4; ++n)
#pragma unroll
        for (int r = 0; r < 4; ++r) {
          float v = ac[n][r] + kcv[kb2][r][n] + jcq[jj][n];
          sum[n] += fmaxf(v, 0.f);
        }
    }
  }

#pragma unroll
  for (int n = 0; n < 4; ++n) {
    float v = sum[n];
    v += __shfl_xor(v, 16, 64);
    v += __shfl_xor(v, 32, 64);
    if (l < 16) RED[w*64 + n*16 + l] = v;
  }
  __syncthreads();
  if (t < 64) {
    float tot = RED[t] + RED[64 + t] + RED[128 + t] + RED[192 + t];
    x8p[(b*32 + i)*64 + t] = tot;            // non-atomic partial
  }
}

// ---------------- k6: reduce x8p over i; x9 = relu(x8/K^3); out = x9 @ out_w.T + out_b ----------------
__global__ __launch_bounds__(64) void k6_out(const float* __restrict__ x8p,
    const float* __restrict__ ow, const float* __restrict__ ob,
    float* __restrict__ out) {
  const int bb = blockIdx.x, t = threadIdx.x;
  float a = 0.f;
#pragma unroll
  for (int i = 0; i < 32; ++i) a += x8p[(bb*32 + i)*64 + t];
  float v = fmaxf(a * (1.f/32768.f), 0.f) * ow[t];
#pragma unroll
  for (int off = 32; off > 0; off >>= 1) v += __shfl_down(v, off, 64);
  if (t == 0) out[bb] = v + ob[0];
}

extern "C" void kernel_launch(void* const* d_in, const int* in_sizes, int n_in,
                              void* d_out, int out_size, void* d_ws, size_t ws_size,
                              hipStream_t stream) {
  const float* x   = (const float*)d_in[0];
  const float* c1w = (const float*)d_in[1];
  const float* c1b = (const float*)d_in[2];
  const float* c2w = (const float*)d_in[3];
  const float* c2b = (const float*)d_in[4];
  const float* fcw = (const float*)d_in[5];
  const float* fcb = (const float*)d_in[6];
  const float* eqw = (const float*)d_in[7];
  const float* eqb = (const float*)d_in[8];
  const float* ow  = (const float*)d_in[9];
  const float* ob  = (const float*)d_in[10];
  float* out = (float*)d_out;

  float* feat = (float*)d_ws;             // 512*64 f32
  float* x8p  = feat + 32768;             // 512*64 f32
  float* W7t  = x8p + 32768;              // 4096 f32
  short* Wtb  = (short*)(W7t + 4096);     // 7*4096 bf16
  short* w2p  = Wtb + 28672;              // 18432 bf16
  short* fcwt = w2p + 18432;              // 3136*64 bf16, [k][e]
  float* s    = (float*)(fcwt + 200704);  // 1024 f32
  float* t7c  = s + 1024;                 // 1024 f32
  (void)in_sizes; (void)n_in; (void)out_size; (void)ws_size;

  hipLaunchKernelGGL(k0_prep, dim3(25), dim3(256), 0, stream,
                     eqw, c2w, fcw, W7t, Wtb, w2p, fcwt);
  hipLaunchKernelGGL(kA_conv, dim3(512), dim3(256), 0, stream,
                     x, c1w, c1b, w2p, c2b, fcwt, fcb, feat);
  hipLaunchKernelGGL(k4b,     dim3(16),  dim3(256), 0, stream,
                     feat, W7t, eqb, s, t7c);
  hipLaunchKernelGGL(k5_mfma, dim3(32, 16), dim3(256), 0, stream,
                     feat, s, Wtb, t7c, x8p);
  hipLaunchKernelGGL(k6_out,  dim3(16),  dim3(64),  0, stream, x8p, ow, ob, out);
}

// Round 9
// 124.748 us; speedup vs baseline: 1.2717x; 1.0094x over previous
//
#include <hip/hip_runtime.h>
#include <hip/hip_bf16.h>

// B=16, K=32, H=W=28, HID=OUT=64, NOPS=8
// ws: feat f32[512*64] | x8p f32[512*64] | W7t f32[4096] | Wtb bf16[7*4096] ([m][e][d])
//     | w2p bf16[18432] | fcwt bf16[3136*64] ([k][e]) | s f32[1024]

typedef __attribute__((ext_vector_type(8))) short short8;
typedef __attribute__((ext_vector_type(4))) float f32x4;

__device__ __forceinline__ f32x4 mfma_bf16(short8 a, short8 b, f32x4 c) {
  return __builtin_amdgcn_mfma_f32_16x16x32_bf16(a, b, c, 0, 0, 0);
}

// float -> bf16 bits, round-to-nearest-even (finite inputs only)
__device__ __forceinline__ unsigned short f2bs(float f) {
  unsigned int u = __float_as_uint(f);
  unsigned int r = u + 0x7fffu + ((u >> 16) & 1u);
  return (unsigned short)(r >> 16);
}
// packed 2xfp32 -> 2xbf16 (v_cvt_pk_bf16_f32 on gfx950)
__device__ __forceinline__ unsigned int pk2(float x, float y) {
  union { __hip_bfloat162 h; unsigned int u; } cv;
  cv.h = __float22bfloat162_rn(make_float2(x, y));
  return cv.u;
}
// unpack 8 bf16 (16B) -> 8 f32
__device__ __forceinline__ void ub8(const short* p, float* f) {
  uint4 u = *(const uint4*)p;
  f[0] = __uint_as_float(u.x << 16); f[1] = __uint_as_float(u.x & 0xffff0000u);
  f[2] = __uint_as_float(u.y << 16); f[3] = __uint_as_float(u.y & 0xffff0000u);
  f[4] = __uint_as_float(u.z << 16); f[5] = __uint_as_float(u.z & 0xffff0000u);
  f[6] = __uint_as_float(u.w << 16); f[7] = __uint_as_float(u.w & 0xffff0000u);
}

// ---------------- k0: weight prep, parallelized (62 tiny blocks) ----------------
// b<8: eqw -> W7t/Wtb | b==8: zero s | b in [9,13): w2p pack (4-way) | b in [13,62): fcwt transpose
__global__ __launch_bounds__(256) void k0_prep(const float* __restrict__ eqw,
    const float* __restrict__ w2, const float* __restrict__ fcw,
    float* __restrict__ W7t, short* __restrict__ Wtb,
    short* __restrict__ w2p, short* __restrict__ fcwt, float* __restrict__ s) {
  const int b = blockIdx.x, t = threadIdx.x;
  if (b < 8) {                 // eq_w (d,e,m) -> W7t f32 / Wtb bf16, [e][d]
    const int m = b;
    for (int idx = t; idx < 4096; idx += 256) {
      int e = idx >> 6, d = idx & 63;
      float v = eqw[d*512 + e*8 + m];
      if (m == 7) W7t[idx] = v;
      else        Wtb[m*4096 + idx] = (short)f2bs(v);
    }
  } else if (b == 8) {         // zero the s accumulator (kA atomicAdds into it)
    for (int idx = t; idx < 1024; idx += 256) s[idx] = 0.f;
  } else if (b < 13) {
    // conv2 weights -> B-fragment layout: w2p[((dd*4+quad)*64 + cout)*8 + s2]
    const int base = (b - 9)*4608;
#pragma unroll
    for (int q = 0; q < 18; ++q) {
      int idx = base + q*256 + t;
      int s2 = idx & 7, c = (idx >> 3) & 63, quad = (idx >> 9) & 3, dd = idx >> 11;
      w2p[idx] = (short)f2bs(w2[c*288 + (quad*8 + s2)*9 + dd]);
    }
  } else {                     // fc_w [e][k] f32 -> fcwt [k][e] bf16 via LDS-tile transpose
    __shared__ short tile[64][65];
    const int j = b - 13;                 // k-range [j*64, j*64+64)
    const int kk = t & 63, eb = t >> 6;   // read: 4 e-rows per pass, coalesced along k
#pragma unroll
    for (int p = 0; p < 16; ++p) {
      int e = p*4 + eb;
      tile[e][kk] = (short)f2bs(fcw[e*3136 + j*64 + kk]);
    }
    __syncthreads();
    const int e = t & 63, kb = t >> 6;    // write: coalesced along e
#pragma unroll
    for (int p = 0; p < 16; ++p) {
      int k = p*4 + kb;
      fcwt[(j*64 + k)*64 + e] = tile[e][k];
    }
  }
}

// ---------------- kA: conv1+pool -> LDS -> conv2(MFMA)+pool -> h2f(LDS) -> coalesced FC -> feat, s ----------------
__global__ __launch_bounds__(256, 2) void kA_conv(const float* __restrict__ x,
    const float* __restrict__ w1, const float* __restrict__ b1,
    const short* __restrict__ w2p, const float* __restrict__ b2,
    const short* __restrict__ fcwt, const float* __restrict__ fcb,
    float* __restrict__ feat, float* __restrict__ s) {
  const int n = blockIdx.x, t = threadIdx.x;
  __shared__ float si[30*30];
  __shared__ float sw[32*9];
  __shared__ float sb[32];
  __shared__ __align__(16) short inT[16*18*40];  // [yy][xx][cin stride 40]
  __shared__ __align__(16) float h2f[3136];      // pooled conv2 out, [c*49 + y*7 + x], f32
  __shared__ float sf4[256];                     // FC partials [w][e]
  const int wv = t >> 6, l = t & 63, quad = l >> 4, col = l & 15;

  // conv2 B fragments: pre-packed by k0, 9 coalesced 16B loads
  const int c_out = wv*16 + col;
  short8 Bq[9];
  {
    const short8* wp = (const short8*)w2p + quad*64 + c_out;
#pragma unroll
    for (int dd = 0; dd < 9; ++dd) Bq[dd] = wp[dd*256];
  }
  const float bb2 = b2[c_out];

  for (int idx = t; idx < 900; idx += 256) si[idx] = 0.f;
  {
    unsigned int* zp = (unsigned int*)inT;
    for (int idx = t; idx < 5760; idx += 256) zp[idx] = 0u;
  }
  for (int idx = t; idx < 288; idx += 256) sw[idx] = w1[idx];
  if (t < 32) sb[t] = b1[t];
  __syncthreads();
  for (int idx = t; idx < 784; idx += 256) {
    int y = idx / 28, xx = idx - y*28;
    si[(y+1)*30 + xx + 1] = x[n*784 + idx];
  }
  __syncthreads();

  // conv1 + relu + maxpool, 4 channels per thread, write bf16 into inT
  {
    const int cg = t & 7;
    float wreg[4][9], breg[4];
#pragma unroll
    for (int cc = 0; cc < 4; ++cc) {
      breg[cc] = sb[cg*4 + cc];
#pragma unroll
      for (int q = 0; q < 9; ++q) wreg[cc][q] = sw[(cg*4 + cc)*9 + q];
    }
    for (int idx = t; idx < 1568; idx += 256) {
      int pos = idx >> 3;
      int py = pos / 14, px = pos - py*14;
      float pt[4][4];
#pragma unroll
      for (int r = 0; r < 4; ++r)
#pragma unroll
        for (int q = 0; q < 4; ++q)
          pt[r][q] = si[(2*py + r)*30 + 2*px + q];
      float res[4];
#pragma unroll
      for (int cc = 0; cc < 4; ++cc) {
        float best = 0.f;
#pragma unroll
        for (int a = 0; a < 2; ++a)
#pragma unroll
          for (int b3 = 0; b3 < 2; ++b3) {
            float v = breg[cc]
              + wreg[cc][0]*pt[a+0][b3+0] + wreg[cc][1]*pt[a+0][b3+1] + wreg[cc][2]*pt[a+0][b3+2]
              + wreg[cc][3]*pt[a+1][b3+0] + wreg[cc][4]*pt[a+1][b3+1] + wreg[cc][5]*pt[a+1][b3+2]
              + wreg[cc][6]*pt[a+2][b3+0] + wreg[cc][7]*pt[a+2][b3+1] + wreg[cc][8]*pt[a+2][b3+2];
            best = fmaxf(best, v);
          }
        res[cc] = best;
      }
      uint2 pkd;
      pkd.x = pk2(res[0], res[1]);
      pkd.y = pk2(res[2], res[3]);
      *(uint2*)&inT[(py+1)*720 + (px+1)*40 + cg*4] = pkd;
    }
  }
  __syncthreads();

  // conv2 via MFMA + maxpool -> h2f (LDS, f32). Wave wv produces channels [16w,16w+16).
  for (int p = 0; p < 7; ++p) {
    short8 Ar[4][3];
#pragma unroll
    for (int rr = 0; rr < 4; ++rr)
#pragma unroll
      for (int dx = 0; dx < 3; ++dx)
        Ar[rr][dx] = *(const short8*)&inT[(2*p + rr)*720 + (col + dx)*40 + quad*8];
    f32x4 a0 = {0.f,0.f,0.f,0.f}, a1 = {0.f,0.f,0.f,0.f};
#pragma unroll
    for (int dy = 0; dy < 3; ++dy)
#pragma unroll
      for (int dx = 0; dx < 3; ++dx) {
        a0 = mfma_bf16(Ar[dy][dx],     Bq[dy*3 + dx], a0);
        a1 = mfma_bf16(Ar[dy + 1][dx], Bq[dy*3 + dx], a1);
      }
#pragma unroll
    for (int a = 0; a < 2; ++a) {
      int px = quad*2 + a;
      if (px < 7) {
        float m0 = fmaxf(fmaxf(a0[2*a], a0[2*a + 1]), fmaxf(a1[2*a], a1[2*a + 1]));
        h2f[c_out*49 + p*7 + px] = fmaxf(m0 + bb2, 0.f);
      }
    }
  }
  // Coalesced fused FC 3136->64 with fcwt [k][e] bf16.
  // Lane l: g = l>>3 (k-offset within octet), s2 = l&7 (e-octet). Wave wv covers
  // k in [784wv, 784wv+784) == exactly the h2f channels it wrote (wave-local, no barrier).
  {
    const int g = l >> 3, s2 = l & 7;
    const short* Wp = fcwt + (wv*784 + g)*64 + s2*8;
    const float* Hp = h2f + wv*784 + g;
    float acc[8] = {0.f,0.f,0.f,0.f,0.f,0.f,0.f,0.f};
#pragma unroll 7
    for (int j = 0; j < 98; ++j) {
      float wf[8]; ub8(Wp + j*512, wf);
      float hk = Hp[j*8];
#pragma unroll
      for (int q = 0; q < 8; ++q) acc[q] += wf[q] * hk;
    }
#pragma unroll
    for (int q = 0; q < 8; ++q) {
      acc[q] += __shfl_xor(acc[q], 8, 64);
      acc[q] += __shfl_xor(acc[q], 16, 64);
      acc[q] += __shfl_xor(acc[q], 32, 64);
    }
    if (g == 0) {
#pragma unroll
      for (int q = 0; q < 8; ++q) sf4[wv*64 + s2*8 + q] = acc[q];
    }
  }
  __syncthreads();
  if (t < 64) {
    float v = sf4[t] + sf4[64 + t] + sf4[128 + t] + sf4[192 + t] + fcb[t];
    v = fmaxf(v, 0.f);
    feat[n*64 + t] = v;
    // set-mean accumulator (s zeroed by k0; device-scope atomics)
    atomicAdd(&s[(n >> 5)*64 + t], v * (1.f/32.f));
  }
}

// ---------------- k5: fused equivariant layer via bf16 MFMA -> x8p partials ----------------
// R0-proven config: (256,2) cap + jcq[8][4] precompute. t7c is computed in the otherwise
// idle w==2 slot (overlaps waves 0-1's MFMA phase) — k4b kernel eliminated.
__global__ __launch_bounds__(256, 2) void k5_mfma(const float* __restrict__ feat,
    const float* __restrict__ s_, const short* __restrict__ Wtb,
    const float* __restrict__ W7t, const float* __restrict__ eqb,
    float* __restrict__ x8p) {
  __shared__ __align__(16) float Fm[32*68];
  __shared__ __align__(16) float FI[64];
  __shared__ __align__(16) float SV[64];
  __shared__ __align__(16) float C0[64];
  __shared__ float C0P[128];
  __shared__ float KCf[32*68];
  __shared__ float JCf[32*68];
  __shared__ float RED[256];
  __shared__ __align__(16) short Fb[32*72];
  __shared__ __align__(16) short QPb[64*72];
  __shared__ __align__(16) short G2b[64*72];
  __shared__ __align__(16) short G3b[64*72];

  const int i = blockIdx.x, b = blockIdx.y, t = threadIdx.x;
  const int w = t >> 6, l = t & 63, quad = l >> 4, col = l & 15;

  for (int idx = t; idx < 2048; idx += 256) {
    int r = idx >> 6, d = idx & 63;
    float v = feat[b*2048 + idx];
    Fm[r*68 + d] = v;
    Fb[r*72 + d] = (short)f2bs(v);
  }
  if (t < 64) { FI[t] = feat[b*2048 + i*64 + t]; SV[t] = s_[b*64 + t]; }
  __syncthreads();

  // P0b: QPb = fi*W0 + s*W1 ; G2b = s*(fi*W2 + s*W4) ; G3b = s*(fi*W3 + s*W5)  (bf16 weights)
  {
    const int e = t >> 2, dbase = (t & 3) * 16;
#pragma unroll
    for (int h = 0; h < 2; ++h) {
      int off = dbase + h*8;
      float w0[8], w1[8], w2[8], w3[8], w4[8], w5[8];
      ub8(&Wtb[0*4096 + e*64 + off], w0);
      ub8(&Wtb[1*4096 + e*64 + off], w1);
      ub8(&Wtb[2*4096 + e*64 + off], w2);
      ub8(&Wtb[3*4096 + e*64 + off], w3);
      ub8(&Wtb[4*4096 + e*64 + off], w4);
      ub8(&Wtb[5*4096 + e*64 + off], w5);
      uint4 qv, g2v, g3v;
      unsigned int* qp = &qv.x;
      unsigned int* g2p = &g2v.x;
      unsigned int* g3p = &g3v.x;
#pragma unroll
      for (int j = 0; j < 4; ++j) {
        float fi0 = FI[off + 2*j],     fi1 = FI[off + 2*j + 1];
        float s0  = SV[off + 2*j],     s1  = SV[off + 2*j + 1];
        float q0 = fi0*w0[2*j]   + s0*w1[2*j];
        float q1 = fi1*w0[2*j+1] + s1*w1[2*j+1];
        float a0 = s0*(fi0*w2[2*j]   + s0*w4[2*j]);
        float a1 = s1*(fi1*w2[2*j+1] + s1*w4[2*j+1]);
        float c0 = s0*(fi0*w3[2*j]   + s0*w5[2*j]);
        float c1 = s1*(fi1*w3[2*j+1] + s1*w5[2*j+1]);
        qp[j]  = pk2(q0, q1);
        g2p[j] = pk2(a0, a1);
        g3p[j] = pk2(c0, c1);
      }
      *(uint4*)&QPb[e*72 + off] = qv;
      *(uint4*)&G2b[e*72 + off] = g2v;
      *(uint4*)&G3b[e*72 + off] = g3v;
    }
  }
  if (t < 128) {
    int e = t & 63, dh = t >> 6;
    const short* W6 = Wtb + 6*4096 + e*64 + dh*32;
    float a = 0.f;
#pragma unroll
    for (int g = 0; g < 4; ++g) {
      float wf[8];
      ub8(&W6[g*8], wf);
#pragma unroll
      for (int dd = 0; dd < 8; ++dd) {
        int d = dh*32 + g*8 + dd;
        float sd = SV[d];
        a += sd*sd*FI[d]*wf[dd];
      }
    }
    C0P[dh*64 + e] = a;
  }
  __syncthreads();

  if (w < 2) {
    const short* G = w ? G3b : G2b;
    float* DST = w ? JCf : KCf;
    short8 Bf[4][2];
#pragma unroll
    for (int n = 0; n < 4; ++n)
#pragma unroll
      for (int s2 = 0; s2 < 2; ++s2)
        Bf[n][s2] = *(const short8*)&G[(n*16 + col)*72 + s2*32 + quad*8];
#pragma unroll
    for (int m = 0; m < 2; ++m) {
      short8 A0 = *(const short8*)&Fb[(m*16 + col)*72 + quad*8];
      short8 A1 = *(const short8*)&Fb[(m*16 + col)*72 + 32 + quad*8];
#pragma unroll
      for (int n = 0; n < 4; ++n) {
        f32x4 z = {0.f, 0.f, 0.f, 0.f};
        f32x4 ac = mfma_bf16(A1, Bf[n][1], mfma_bf16(A0, Bf[n][0], z));
#pragma unroll
        for (int r = 0; r < 4; ++r)
          DST[(m*16 + quad*4 + r)*68 + n*16 + col] = ac[r];
      }
    }
  } else if (w == 2) {
    // t7c fold (was kernel k4b): t7[e=l] = sum_d s_d^3 * W7t[e][d] + eqb[e]
    const float* W7 = W7t + l*64;
    float t7 = 0.f;
#pragma unroll 8
    for (int d = 0; d < 64; ++d) {
      float sv = SV[d];
      t7 += sv*sv*sv * W7[d];
    }
    C0[l] = C0P[l] + C0P[64 + l] + t7 + eqb[l];
  }
  __syncthreads();

  float c0v[4];
#pragma unroll
  for (int n = 0; n < 4; ++n) c0v[n] = C0[n*16 + col];
  float jcq[8][4];
#pragma unroll
  for (int jj = 0; jj < 8; ++jj)
#pragma unroll
    for (int n = 0; n < 4; ++n)
      jcq[jj][n] = JCf[(w*8 + jj)*68 + n*16 + col] + c0v[n];
  float kcv[2][4][4];
#pragma unroll
  for (int kb2 = 0; kb2 < 2; ++kb2)
#pragma unroll
    for (int r = 0; r < 4; ++r)
#pragma unroll
      for (int n = 0; n < 4; ++n)
        kcv[kb2][r][n] = KCf[(kb2*16 + quad*4 + r)*68 + n*16 + col];
  short8 Bq[4][2];
#pragma unroll
  for (int n = 0; n < 4; ++n)
#pragma unroll
    for (int s2 = 0; s2 < 2; ++s2)
      Bq[n][s2] = *(const short8*)&QPb[(n*16 + col)*72 + s2*32 + quad*8];

  float4 fkv[2][4];
#pragma unroll
  for (int kb2 = 0; kb2 < 2; ++kb2) {
    const float* fk = &Fm[(kb2*16 + col)*68 + quad*8];
    fkv[kb2][0] = *(const float4*)(fk);
    fkv[kb2][1] = *(const float4*)(fk + 4);
    fkv[kb2][2] = *(const float4*)(fk + 32);
    fkv[kb2][3] = *(const float4*)(fk + 36);
  }

  float sum[4] = {0.f, 0.f, 0.f, 0.f};
  union SU { short8 v; unsigned int u[4]; };

#pragma unroll
  for (int jj = 0; jj < 8; ++jj) {
    const float* fj = &Fm[(w*8 + jj)*68 + quad*8];
    float4 j0 = *(const float4*)(fj);
    float4 j1 = *(const float4*)(fj + 4);
    float4 j2 = *(const float4*)(fj + 32);
    float4 j3 = *(const float4*)(fj + 36);
#pragma unroll
    for (int kb2 = 0; kb2 < 2; ++kb2) {
      float4 k0 = fkv[kb2][0], k1 = fkv[kb2][1];
      float4 k2v = fkv[kb2][2], k3v = fkv[kb2][3];
      SU A0, A1;
      A0.u[0] = pk2(j0.x*k0.x, j0.y*k0.y);
      A0.u[1] = pk2(j0.z*k0.z, j0.w*k0.w);
      A0.u[2] = pk2(j1.x*k1.x, j1.y*k1.y);
      A0.u[3] = pk2(j1.z*k1.z, j1.w*k1.w);
      A1.u[0] = pk2(j2.x*k2v.x, j2.y*k2v.y);
      A1.u[1] = pk2(j2.z*k2v.z, j2.w*k2v.w);
      A1.u[2] = pk2(j3.x*k3v.x, j3.y*k3v.y);
      A1.u[3] = pk2(j3.z*k3v.z, j3.w*k3v.w);
      f32x4 ac[4];
#pragma unroll
      for (int n = 0; n < 4; ++n) {
        f32x4 z = {0.f, 0.f, 0.f, 0.f};
        ac[n] = mfma_bf16(A1.v, Bq[n][1], mfma_bf16(A0.v, Bq[n][0], z));
      }
#pragma unroll
      for (int n = 0; n < 4; ++n)
#pragma unroll
        for (int r = 0; r < 4; ++r) {
          float v = ac[n][r] + kcv[kb2][r][n] + jcq[jj][n];
          sum[n] += fmaxf(v, 0.f);
        }
    }
  }

#pragma unroll
  for (int n = 0; n < 4; ++n) {
    float v = sum[n];
    v += __shfl_xor(v, 16, 64);
    v += __shfl_xor(v, 32, 64);
    if (l < 16) RED[w*64 + n*16 + l] = v;
  }
  __syncthreads();
  if (t < 64) {
    float tot = RED[t] + RED[64 + t] + RED[128 + t] + RED[192 + t];
    x8p[(b*32 + i)*64 + t] = tot;            // non-atomic partial
  }
}

// ---------------- k6: reduce x8p over i; x9 = relu(x8/K^3); out = x9 @ out_w.T + out_b ----------------
__global__ __launch_bounds__(64) void k6_out(const float* __restrict__ x8p,
    const float* __restrict__ ow, const float* __restrict__ ob,
    float* __restrict__ out) {
  const int bb = blockIdx.x, t = threadIdx.x;
  float a = 0.f;
#pragma unroll
  for (int i = 0; i < 32; ++i) a += x8p[(bb*32 + i)*64 + t];
  float v = fmaxf(a * (1.f/32768.f), 0.f) * ow[t];
#pragma unroll
  for (int off = 32; off > 0; off >>= 1) v += __shfl_down(v, off, 64);
  if (t == 0) out[bb] = v + ob[0];
}

extern "C" void kernel_launch(void* const* d_in, const int* in_sizes, int n_in,
                              void* d_out, int out_size, void* d_ws, size_t ws_size,
                              hipStream_t stream) {
  const float* x   = (const float*)d_in[0];
  const float* c1w = (const float*)d_in[1];
  const float* c1b = (const float*)d_in[2];
  const float* c2w = (const float*)d_in[3];
  const float* c2b = (const float*)d_in[4];
  const float* fcw = (const float*)d_in[5];
  const float* fcb = (const float*)d_in[6];
  const float* eqw = (const float*)d_in[7];
  const float* eqb = (const float*)d_in[8];
  const float* ow  = (const float*)d_in[9];
  const float* ob  = (const float*)d_in[10];
  float* out = (float*)d_out;

  float* feat = (float*)d_ws;             // 512*64 f32
  float* x8p  = feat + 32768;             // 512*64 f32
  float* W7t  = x8p + 32768;              // 4096 f32
  short* Wtb  = (short*)(W7t + 4096);     // 7*4096 bf16
  short* w2p  = Wtb + 28672;              // 18432 bf16
  short* fcwt = w2p + 18432;              // 3136*64 bf16, [k][e]
  float* s    = (float*)(fcwt + 200704);  // 1024 f32 (zeroed by k0, accumulated by kA)
  (void)in_sizes; (void)n_in; (void)out_size; (void)ws_size;

  hipLaunchKernelGGL(k0_prep, dim3(62), dim3(256), 0, stream,
                     eqw, c2w, fcw, W7t, Wtb, w2p, fcwt, s);
  hipLaunchKernelGGL(kA_conv, dim3(512), dim3(256), 0, stream,
                     x, c1w, c1b, w2p, c2b, fcwt, fcb, feat, s);
  hipLaunchKernelGGL(k5_mfma, dim3(32, 16), dim3(256), 0, stream,
                     feat, s, Wtb, W7t, eqb, x8p);
  hipLaunchKernelGGL(k6_out,  dim3(16),  dim3(64),  0, stream, x8p, ow, ob, out);
}